// Round 4
// baseline (1331.810 us; speedup 1.0000x reference)
//
#include <hip/hip_runtime.h>
#include <stdint.h>

// ---------------------------------------------------------------------------
// AdjCompute R4: all heavy passes on mfma_f32_32x32x16_bf16 so weights live
// in MFMA fragments (4 VGPRs) instead of per-FMA global reloads (R3's 7x
// VALU bloat).
//
// Pipeline: k_prep -> k_layer1(h1+stats1) -> bnprep1 -> k_stats2(stats2 of
// d=h2-b2) -> bnprep2(fixup+fold b2) -> k_fuse3(h1->h2->act2->h3, store h3
// incl b3 + stats3) -> bnprep3 -> k_stats4(stats4 of h4) -> bnprep4(fold
// bn4 into W4f/b4f) -> k_last(h3->h4->out).
//
// ws layout (floats):
//   [0..32)    stats1 (sum16, ssq16)
//   [32..64)   stats2raw (S16, Q16 of d = h2_pre - b2)
//   [64..80)   stats3 (sum8, ssq8)
//   [80..96)   stats4 (sum8, ssq8)
//   [128..192) bn1: sc[0..16), sh[32..48)
//   [192..256) bn2 (applies to d; b2 folded into shift)
//   [256..320) bn3
//   [320..384) w4f[8][8]  (bn4-folded W4)
//   [384..392) b4f[8]
//   byte 8192:            bufA h1: NN*16 bf16 = 75,497,472 B
//   byte 8192+75497472:   bufB h3: NN*8  bf16 = 37,748,736 B
// MFMA 32x32x16 layouts [m74/m101]:
//   A[m=lane&31][k=(lane>>5)*8+j], B[k=(lane>>5)*8+j][n=lane&31],
//   D col n=lane&31, row m=(reg&3)+8*(reg>>2)+4*(lane>>5).
// ---------------------------------------------------------------------------

#define NPTS 1536
#define NN   2359296u
static constexpr float FNN   = 2359296.0f;
static constexpr float EPS   = 1e-5f;
static constexpr float SLOPE = 0.01f;
static constexpr float INV_M = 1.0f / 2359296.0f;

typedef __attribute__((ext_vector_type(8)))  short bf16x8;
typedef __attribute__((ext_vector_type(16))) float f32x16;
union frag8 { int4 i; bf16x8 v; };

__device__ __forceinline__ float bflo(unsigned u) {
    return __builtin_bit_cast(float, u << 16);
}
__device__ __forceinline__ float bfhi(unsigned u) {
    return __builtin_bit_cast(float, u & 0xffff0000u);
}
__device__ __forceinline__ unsigned short f2bf(float f) {   // RNE
    unsigned u = __builtin_bit_cast(unsigned, f);
    u += 0x7fffu + ((u >> 16) & 1u);
    return (unsigned short)(u >> 16);
}
__device__ __forceinline__ unsigned pack2(float lo, float hi) {  // RNE pair
    return (unsigned)f2bf(lo) | ((unsigned)f2bf(hi) << 16);
}
__device__ __forceinline__ unsigned packtr(float lo, float hi) { // trunc pair
    unsigned a = __builtin_bit_cast(unsigned, lo);
    unsigned b = __builtin_bit_cast(unsigned, hi);
    return (a >> 16) | (b & 0xffff0000u);
}
__device__ __forceinline__ float lrelu(float t) {
    return fmaxf(t, t * SLOPE);
}
__device__ __forceinline__ frag8 zero_frag() {
    frag8 f; f.i = make_int4(0, 0, 0, 0); return f;
}

// --------------------------------------------------------------------------
__global__ __launch_bounds__(256) void k_prep(float* __restrict__ ws) {
    int t = threadIdx.x;
    if (t < 96) ws[t] = 0.0f;
}

// standard bn: stats=[sum CI][ssq CI] -> bn[c]=sc, bn[32+c]=sh
__global__ __launch_bounds__(64) void k_bnprep(
        const float* __restrict__ stats, const float* __restrict__ g,
        const float* __restrict__ be, int CI, float* __restrict__ bn) {
    int c = threadIdx.x;
    if (c < CI) {
        float mu  = stats[c] * INV_M;
        float var = fmaf(-mu, mu, stats[CI + c] * INV_M);
        float sc  = g[c] * rsqrtf(var + EPS);
        bn[c]      = sc;
        bn[32 + c] = fmaf(-mu, sc, be[c]);
    }
}

// bn2 from raw moments of d = h2_pre - b2; fold b2 into shift
__global__ __launch_bounds__(64) void k_bnprep2(
        const float* __restrict__ raw, const float* __restrict__ g,
        const float* __restrict__ be, const float* __restrict__ b,
        float* __restrict__ bn) {
    int c = threadIdx.x;
    if (c < 16) {
        float S = raw[c], Q = raw[16 + c], bc = b[c];
        float sum = S + FNN * bc;
        float ssq = Q + 2.0f * bc * S + FNN * bc * bc;
        float mu  = sum * INV_M;
        float var = fmaf(-mu, mu, ssq * INV_M);
        float sc  = g[c] * rsqrtf(var + EPS);
        float sh  = fmaf(-mu, sc, be[c]);
        bn[c]      = sc;
        bn[32 + c] = fmaf(sc, bc, sh);   // applies directly to d
    }
}

// fold bn4 into W4: w4f = sc4[o]*W4[o][c], b4f = sc4[o]*b4[o]+sh4[o]
__global__ __launch_bounds__(64) void k_bnprep4(
        const float* __restrict__ stats, const float* __restrict__ g,
        const float* __restrict__ be, const float* __restrict__ W4,
        const float* __restrict__ b4, float* __restrict__ w4f,
        float* __restrict__ b4f) {
    int t = threadIdx.x;
    if (t < 64) {
        int o = t >> 3;
        float mu  = stats[o] * INV_M;
        float var = fmaf(-mu, mu, stats[8 + o] * INV_M);
        float sc  = g[o] * rsqrtf(var + EPS);
        w4f[t] = sc * W4[t];
        if (t < 8) {
            float muo  = stats[t] * INV_M;
            float varo = fmaf(-muo, muo, stats[8 + t] * INV_M);
            float sco  = g[t] * rsqrtf(varo + EPS);
            float sho  = fmaf(-muo, sco, be[t]);
            b4f[t] = fmaf(sco, b4[t], sho);
        }
    }
}

// --------------------------------------------------------------------------
// Layer 1 (16x16x32 MFMA): h1[n,m,o] = b1[o] + sum_c W1[o,c]*|x[m,c]-x[n,c]|
// wave = 16m x 16o x 1n; 16 n per wave; grid 2304 blocks (9216 waves).
typedef __attribute__((ext_vector_type(4))) float f32x4;
__global__ __launch_bounds__(256) void k_layer1(
        const float* __restrict__ x, const float* __restrict__ W1,
        const float* __restrict__ b1, unsigned short* __restrict__ outb,
        float* __restrict__ stats) {
    int lane = threadIdx.x & 63;
    int wv   = threadIdx.x >> 6;
    int gid  = blockIdx.x * 4 + wv;
    int mt   = gid % 96;
    int nc   = gid / 96;          // 0..95
    int o    = lane & 15;
    int quad = lane >> 4;
    int cb   = quad * 8;

    const float* wr = W1 + o * 64 + cb;
    float4 w0 = *(const float4*)(wr);
    float4 w1 = *(const float4*)(wr + 4);
    float4 w2 = *(const float4*)(wr + 32);
    float4 w3 = *(const float4*)(wr + 36);
    frag8 fb1, fb2;
    fb1.i = make_int4(pack2(w0.x, w0.y), pack2(w0.z, w0.w),
                      pack2(w1.x, w1.y), pack2(w1.z, w1.w));
    fb2.i = make_int4(pack2(w2.x, w2.y), pack2(w2.z, w2.w),
                      pack2(w3.x, w3.y), pack2(w3.z, w3.w));

    const float* xr = x + (mt * 16 + o) * 64 + cb;
    float4 xa0 = *(const float4*)(xr);
    float4 xa1 = *(const float4*)(xr + 4);
    float4 xa2 = *(const float4*)(xr + 32);
    float4 xa3 = *(const float4*)(xr + 36);

    float bias = b1[o];
    float lsum = 0.f, lssq = 0.f;
    unsigned mrow = mt * 16 + quad * 4;

    int n0 = nc * 16;
    const float* xp = x + (size_t)n0 * 64 + cb;
    float4 uA0 = *(const float4*)(xp);
    float4 uA1 = *(const float4*)(xp + 4);
    float4 uA2 = *(const float4*)(xp + 32);
    float4 uA3 = *(const float4*)(xp + 36);
    const float* xq = x + (size_t)(n0 + 1) * 64 + cb;
    float4 uB0 = *(const float4*)(xq);
    float4 uB1 = *(const float4*)(xq + 4);
    float4 uB2 = *(const float4*)(xq + 32);
    float4 uB3 = *(const float4*)(xq + 36);

    auto body = [&](int n, float4& u0, float4& u1, float4& u2, float4& u3,
                    int pf) {
        frag8 fa1, fa2;
        fa1.i = make_int4(
            packtr(fabsf(xa0.x - u0.x), fabsf(xa0.y - u0.y)),
            packtr(fabsf(xa0.z - u0.z), fabsf(xa0.w - u0.w)),
            packtr(fabsf(xa1.x - u1.x), fabsf(xa1.y - u1.y)),
            packtr(fabsf(xa1.z - u1.z), fabsf(xa1.w - u1.w)));
        fa2.i = make_int4(
            packtr(fabsf(xa2.x - u2.x), fabsf(xa2.y - u2.y)),
            packtr(fabsf(xa2.z - u2.z), fabsf(xa2.w - u2.w)),
            packtr(fabsf(xa3.x - u3.x), fabsf(xa3.y - u3.y)),
            packtr(fabsf(xa3.z - u3.z), fabsf(xa3.w - u3.w)));
        const float* xf = x + (size_t)pf * 64 + cb;
        u0 = *(const float4*)(xf);
        u1 = *(const float4*)(xf + 4);
        u2 = *(const float4*)(xf + 32);
        u3 = *(const float4*)(xf + 36);
        f32x4 acc = {bias, bias, bias, bias};
        acc = __builtin_amdgcn_mfma_f32_16x16x32_bf16(fa1.v, fb1.v, acc, 0, 0, 0);
        acc = __builtin_amdgcn_mfma_f32_16x16x32_bf16(fa2.v, fb2.v, acc, 0, 0, 0);
        size_t base = ((size_t)n * NPTS + mrow) * 16 + o;
#pragma unroll
        for (int r = 0; r < 4; r++) {
            float v = acc[r];
            lsum += v;
            lssq = fmaf(v, v, lssq);
            outb[base + (unsigned)r * 16u] = f2bf(v);
        }
    };

#pragma unroll 1
    for (int i = 0; i < 16; i += 2) {
        int pfA = n0 + ((i + 2 < 16) ? i + 2 : 15);
        int pfB = n0 + ((i + 3 < 16) ? i + 3 : 15);
        body(n0 + i,     uA0, uA1, uA2, uA3, pfA);
        body(n0 + i + 1, uB0, uB1, uB2, uB3, pfB);
    }

    lsum += __shfl_xor(lsum, 16); lssq += __shfl_xor(lssq, 16);
    lsum += __shfl_xor(lsum, 32); lssq += __shfl_xor(lssq, 32);
    __shared__ float red[4][32];
    if (quad == 0) { red[wv][o] = lsum; red[wv][16 + o] = lssq; }
    __syncthreads();
    if (threadIdx.x < 32) {
        float v = red[0][threadIdx.x] + red[1][threadIdx.x] +
                  red[2][threadIdx.x] + red[3][threadIdx.x];
        atomicAdd(stats + threadIdx.x, v);
    }
}

// --------------------------------------------------------------------------
// stats2: read h1, act1, MFMA vs W2, accumulate S/Q of d = h2_pre - b2.
// grid 2048 x 4 waves; 9 tiles of 32 pos per wave (73728 tiles total).
__global__ __launch_bounds__(256) void k_stats2(
        const unsigned short* __restrict__ h1, const float* __restrict__ bn1,
        const float* __restrict__ W2, float* __restrict__ raw) {
    int lane = threadIdx.x & 63;
    int gid  = blockIdx.x * 4 + (threadIdx.x >> 6);
    int oc   = lane & 31;
    int kh   = lane >> 5;

    // bn1 slices for this lane's 8 channels (c = kh*8+j)
    float4 s0 = *(const float4*)(bn1 + kh * 8);
    float4 s1 = *(const float4*)(bn1 + kh * 8 + 4);
    float4 t0 = *(const float4*)(bn1 + 32 + kh * 8);
    float4 t1 = *(const float4*)(bn1 + 32 + kh * 8 + 4);

    frag8 fb = zero_frag();
    if (oc < 16) {
        const float* w = W2 + oc * 16 + kh * 8;
        float4 a = *(const float4*)(w);
        float4 b = *(const float4*)(w + 4);
        fb.i = make_int4(pack2(a.x, a.y), pack2(a.z, a.w),
                         pack2(b.x, b.y), pack2(b.z, b.w));
    }
    f32x16 z;
#pragma unroll
    for (int r = 0; r < 16; r++) z[r] = 0.0f;

    float sacc = 0.f, qacc = 0.f;
#pragma unroll 1
    for (int i = 0; i < 9; i++) {
        size_t p = (size_t)(gid * 9 + i) * 32 + oc;
        uint4 v = *(const uint4*)(h1 + p * 16 + kh * 8);
        float a0 = bflo(v.x), a1 = bfhi(v.x), a2 = bflo(v.y), a3 = bfhi(v.y);
        float a4 = bflo(v.z), a5 = bfhi(v.z), a6 = bflo(v.w), a7 = bfhi(v.w);
        a0 = lrelu(fmaf(a0, s0.x, t0.x)); a1 = lrelu(fmaf(a1, s0.y, t0.y));
        a2 = lrelu(fmaf(a2, s0.z, t0.z)); a3 = lrelu(fmaf(a3, s0.w, t0.w));
        a4 = lrelu(fmaf(a4, s1.x, t1.x)); a5 = lrelu(fmaf(a5, s1.y, t1.y));
        a6 = lrelu(fmaf(a6, s1.z, t1.z)); a7 = lrelu(fmaf(a7, s1.w, t1.w));
        frag8 fa;
        fa.i = make_int4(pack2(a0, a1), pack2(a2, a3),
                         pack2(a4, a5), pack2(a6, a7));
        f32x16 d = __builtin_amdgcn_mfma_f32_32x32x16_bf16(fa.v, fb.v, z, 0, 0, 0);
#pragma unroll
        for (int r = 0; r < 16; r++) {
            sacc += d[r];
            qacc = fmaf(d[r], d[r], qacc);
        }
    }
    sacc += __shfl_xor(sacc, 32);
    qacc += __shfl_xor(qacc, 32);
    if (lane < 16) {
        atomicAdd(raw + lane, sacc);
        atomicAdd(raw + 16 + lane, qacc);
    }
}

// --------------------------------------------------------------------------
// fuse3: h1 -> act1 -> (MFMA W2) d -> act2 -> LDS transpose -> (MFMA W3)
// -> h3 = d2 + b3 -> store bufB + stats3.
__global__ __launch_bounds__(256) void k_fuse3(
        const unsigned short* __restrict__ h1, unsigned* __restrict__ outb,
        const float* __restrict__ bn1, const float* __restrict__ W2,
        const float* __restrict__ bn2, const float* __restrict__ W3,
        const float* __restrict__ b3, float* __restrict__ stats3) {
    int lane = threadIdx.x & 63;
    int wv   = threadIdx.x >> 6;
    int gid  = blockIdx.x * 4 + wv;
    int oc   = lane & 31;
    int kh   = lane >> 5;

    float4 s0 = *(const float4*)(bn1 + kh * 8);
    float4 s1 = *(const float4*)(bn1 + kh * 8 + 4);
    float4 t0 = *(const float4*)(bn1 + 32 + kh * 8);
    float4 t1 = *(const float4*)(bn1 + 32 + kh * 8 + 4);

    frag8 fb2 = zero_frag(), fw3 = zero_frag();
    if (oc < 16) {
        const float* w = W2 + oc * 16 + kh * 8;
        float4 a = *(const float4*)(w);
        float4 b = *(const float4*)(w + 4);
        fb2.i = make_int4(pack2(a.x, a.y), pack2(a.z, a.w),
                          pack2(b.x, b.y), pack2(b.z, b.w));
    }
    if (oc < 8) {
        const float* w = W3 + oc * 16 + kh * 8;
        float4 a = *(const float4*)(w);
        float4 b = *(const float4*)(w + 4);
        fw3.i = make_int4(pack2(a.x, a.y), pack2(a.z, a.w),
                          pack2(b.x, b.y), pack2(b.z, b.w));
    }
    float sc2 = (oc < 16) ? bn2[oc] : 0.f;
    float sh2 = (oc < 16) ? bn2[32 + oc] : 0.f;
    float4 b3q = *(const float4*)(b3 + kh * 4);   // b3[r + 4*kh]

    f32x16 z;
#pragma unroll
    for (int r = 0; r < 16; r++) z[r] = 0.0f;

    __shared__ unsigned short Tz[4][768];   // [pos][c], row stride 24 ushorts
    unsigned short* T = Tz[wv];

    float s3[4] = {0.f, 0.f, 0.f, 0.f};
    float q3[4] = {0.f, 0.f, 0.f, 0.f};

#pragma unroll 1
    for (int i = 0; i < 9; i++) {
        size_t tile = (size_t)(gid * 9 + i);
        size_t p = tile * 32 + oc;
        uint4 v = *(const uint4*)(h1 + p * 16 + kh * 8);
        float a0 = bflo(v.x), a1 = bfhi(v.x), a2 = bflo(v.y), a3 = bfhi(v.y);
        float a4 = bflo(v.z), a5 = bfhi(v.z), a6 = bflo(v.w), a7 = bfhi(v.w);
        a0 = lrelu(fmaf(a0, s0.x, t0.x)); a1 = lrelu(fmaf(a1, s0.y, t0.y));
        a2 = lrelu(fmaf(a2, s0.z, t0.z)); a3 = lrelu(fmaf(a3, s0.w, t0.w));
        a4 = lrelu(fmaf(a4, s1.x, t1.x)); a5 = lrelu(fmaf(a5, s1.y, t1.y));
        a6 = lrelu(fmaf(a6, s1.z, t1.z)); a7 = lrelu(fmaf(a7, s1.w, t1.w));
        frag8 fa;
        fa.i = make_int4(pack2(a0, a1), pack2(a2, a3),
                         pack2(a4, a5), pack2(a6, a7));
        f32x16 d = __builtin_amdgcn_mfma_f32_32x32x16_bf16(fa.v, fb2.v, z, 0, 0, 0);
        // act2 + LDS transpose write ([pos][c] bf16, stride 24)
        if (oc < 16) {
#pragma unroll
            for (int r = 0; r < 16; r++) {
                float t = lrelu(fmaf(d[r], sc2, sh2));
                int posr = (r & 3) + 8 * (r >> 2) + 4 * kh;
                T[posr * 24 + oc] = f2bf(t);
            }
        }
        __builtin_amdgcn_s_waitcnt(0);   // lgkmcnt(0): drain ds_writes (wave-local)
        frag8 fbB;
        fbB.i = *(const int4*)(T + oc * 24 + kh * 8);
        f32x16 d2 = __builtin_amdgcn_mfma_f32_32x32x16_bf16(fw3.v, fbB.v, z, 0, 0, 0);
        float h30 = d2[0] + b3q.x, h31 = d2[1] + b3q.y;
        float h32 = d2[2] + b3q.z, h33 = d2[3] + b3q.w;
        s3[0] += h30; q3[0] = fmaf(h30, h30, q3[0]);
        s3[1] += h31; q3[1] = fmaf(h31, h31, q3[1]);
        s3[2] += h32; q3[2] = fmaf(h32, h32, q3[2]);
        s3[3] += h33; q3[3] = fmaf(h33, h33, q3[3]);
        // store h3[pos][8ch]: this lane covers ch kh*4..kh*4+3 of pos=oc
        uint2 pk = make_uint2(pack2(h30, h31), pack2(h32, h33));
        *(uint2*)((char*)outb + (tile * 32 + oc) * 16 + kh * 8) = pk;
    }
#pragma unroll
    for (int off = 1; off < 32; off <<= 1) {
#pragma unroll
        for (int r = 0; r < 4; r++) {
            s3[r] += __shfl_xor(s3[r], off);
            q3[r] += __shfl_xor(q3[r], off);
        }
    }
    if (oc == 0) {
#pragma unroll
        for (int r = 0; r < 4; r++) {
            atomicAdd(stats3 + (r + 4 * kh), s3[r]);
            atomicAdd(stats3 + 8 + (r + 4 * kh), q3[r]);
        }
    }
}

// --------------------------------------------------------------------------
// stats4: read h3, act3, MFMA vs W4, accumulate stats of h4 (incl b4).
__global__ __launch_bounds__(256) void k_stats4(
        const unsigned short* __restrict__ h3, const float* __restrict__ bn3,
        const float* __restrict__ W4, const float* __restrict__ b4,
        float* __restrict__ stats4) {
    int lane = threadIdx.x & 63;
    int gid  = blockIdx.x * 4 + (threadIdx.x >> 6);
    int oc   = lane & 31;
    int kh   = lane >> 5;

    float4 s0 = *(const float4*)(bn3);
    float4 s1 = *(const float4*)(bn3 + 4);
    float4 t0 = *(const float4*)(bn3 + 32);
    float4 t1 = *(const float4*)(bn3 + 36);

    frag8 fb = zero_frag();
    if (kh == 0 && oc < 8) {
        const float* w = W4 + oc * 8;
        float4 a = *(const float4*)(w);
        float4 b = *(const float4*)(w + 4);
        fb.i = make_int4(pack2(a.x, a.y), pack2(a.z, a.w),
                         pack2(b.x, b.y), pack2(b.z, b.w));
    }
    float b4o = (oc < 8) ? b4[oc] : 0.f;
    f32x16 z;
#pragma unroll
    for (int r = 0; r < 16; r++) z[r] = 0.0f;

    float sacc = 0.f, qacc = 0.f;
#pragma unroll 1
    for (int i = 0; i < 9; i++) {
        size_t p = (size_t)(gid * 9 + i) * 32 + oc;
        frag8 fa = zero_frag();
        if (kh == 0) {
            uint4 v = *(const uint4*)(h3 + p * 8);
            float a0 = bflo(v.x), a1 = bfhi(v.x), a2 = bflo(v.y), a3 = bfhi(v.y);
            float a4 = bflo(v.z), a5 = bfhi(v.z), a6 = bflo(v.w), a7 = bfhi(v.w);
            a0 = lrelu(fmaf(a0, s0.x, t0.x)); a1 = lrelu(fmaf(a1, s0.y, t0.y));
            a2 = lrelu(fmaf(a2, s0.z, t0.z)); a3 = lrelu(fmaf(a3, s0.w, t0.w));
            a4 = lrelu(fmaf(a4, s1.x, t1.x)); a5 = lrelu(fmaf(a5, s1.y, t1.y));
            a6 = lrelu(fmaf(a6, s1.z, t1.z)); a7 = lrelu(fmaf(a7, s1.w, t1.w));
            fa.i = make_int4(pack2(a0, a1), pack2(a2, a3),
                             pack2(a4, a5), pack2(a6, a7));
        }
        f32x16 d = __builtin_amdgcn_mfma_f32_32x32x16_bf16(fa.v, fb.v, z, 0, 0, 0);
#pragma unroll
        for (int r = 0; r < 16; r++) {
            float t = d[r] + b4o;
            sacc += t;
            qacc = fmaf(t, t, qacc);
        }
    }
    sacc += __shfl_xor(sacc, 32);
    qacc += __shfl_xor(qacc, 32);
    if (lane < 8) {
        atomicAdd(stats4 + lane, sacc);
        atomicAdd(stats4 + 8 + lane, qacc);
    }
}

// --------------------------------------------------------------------------
// last: h3 -> act3 -> h4 via bn4-folded W4f -> lrelu -> dot W5 -> out
__global__ __launch_bounds__(256) void k_last(
        const uint4* __restrict__ inb, const float* __restrict__ bn3,
        const float* __restrict__ w4f, const float* __restrict__ b4f,
        const float* __restrict__ W5, const float* __restrict__ b5,
        float* __restrict__ out) {
    unsigned p = blockIdx.x * 256u + threadIdx.x;
    uint4 v = inb[p];
    float a[8];
    a[0] = bflo(v.x); a[1] = bfhi(v.x);
    a[2] = bflo(v.y); a[3] = bfhi(v.y);
    a[4] = bflo(v.z); a[5] = bfhi(v.z);
    a[6] = bflo(v.w); a[7] = bfhi(v.w);
#pragma unroll
    for (int c = 0; c < 8; c++)
        a[c] = lrelu(fmaf(a[c], bn3[c], bn3[32 + c]));
    float acc = b5[0];
#pragma unroll
    for (int o = 0; o < 8; o++) {
        float h = b4f[o];
#pragma unroll
        for (int c = 0; c < 8; c++)
            h = fmaf(a[c], w4f[o * 8 + c], h);
        acc = fmaf(lrelu(h), W5[o], acc);
    }
    out[p] = acc;
}

// --------------------------------------------------------------------------
extern "C" void kernel_launch(void* const* d_in, const int* in_sizes, int n_in,
                              void* d_out, int out_size, void* d_ws,
                              size_t ws_size, hipStream_t stream) {
    const float* x   = (const float*)d_in[0];
    const float* W1  = (const float*)d_in[1];
    const float* b1  = (const float*)d_in[2];
    const float* g1  = (const float*)d_in[3];
    const float* be1 = (const float*)d_in[4];
    const float* W2  = (const float*)d_in[5];
    const float* b2  = (const float*)d_in[6];
    const float* g2  = (const float*)d_in[7];
    const float* be2 = (const float*)d_in[8];
    const float* W3  = (const float*)d_in[9];
    const float* b3  = (const float*)d_in[10];
    const float* g3  = (const float*)d_in[11];
    const float* be3 = (const float*)d_in[12];
    const float* W4  = (const float*)d_in[13];
    const float* b4  = (const float*)d_in[14];
    const float* g4  = (const float*)d_in[15];
    const float* be4 = (const float*)d_in[16];
    const float* W5  = (const float*)d_in[17];
    const float* b5  = (const float*)d_in[18];

    float* ws        = (float*)d_ws;
    float* stats1    = ws + 0;
    float* stats2raw = ws + 32;
    float* stats3    = ws + 64;
    float* stats4    = ws + 80;
    float* bn1       = ws + 128;
    float* bn2       = ws + 192;
    float* bn3       = ws + 256;
    float* w4f       = ws + 320;
    float* b4f       = ws + 384;
    unsigned short* bufA = (unsigned short*)((char*)d_ws + 8192);
    unsigned short* bufB =
        (unsigned short*)((char*)d_ws + 8192 + (size_t)NN * 32u);

    k_prep<<<1, 256, 0, stream>>>(ws);
    k_layer1<<<2304, 256, 0, stream>>>(x, W1, b1, bufA, stats1);
    k_bnprep<<<1, 64, 0, stream>>>(stats1, g1, be1, 16, bn1);
    k_stats2<<<2048, 256, 0, stream>>>(bufA, bn1, W2, stats2raw);
    k_bnprep2<<<1, 64, 0, stream>>>(stats2raw, g2, be2, b2, bn2);
    k_fuse3<<<2048, 256, 0, stream>>>(bufA, (unsigned*)bufB, bn1, W2, bn2,
                                      W3, b3, stats3);
    k_bnprep<<<1, 64, 0, stream>>>(stats3, g3, be3, 8, bn3);
    k_stats4<<<2048, 256, 0, stream>>>(bufB, bn3, W4, b4, stats4);
    k_bnprep4<<<1, 64, 0, stream>>>(stats4, g4, be4, W4, b4, w4f, b4f);
    k_last<<<9216, 256, 0, stream>>>((const uint4*)bufB, bn3, w4f, b4f,
                                     W5, b5, (float*)d_out);
}

// Round 5
// 286.692 us; speedup vs baseline: 4.6454x; 4.6454x over previous
//
#include <hip/hip_runtime.h>
#include <stdint.h>

// ---------------------------------------------------------------------------
// AdjCompute R5.
// Measured lessons: R3 = in-loop weight loads -> 7x VALU bloat (99us/pass).
// R4 = per-iter LDS round-trip + waitcnt(0) drain -> latency serialization
// (844us, all pipes <3.2% busy). R5: VALU mids with weights HOISTED to VGPRs
// via output-channel split (og = tid&3 owns 4 out-ch -> 32..64 weight floats,
// full-unroll const indexing); cross-lane act2 exchange in fuse3 via
// shfl_xor with xor-ordered weight pregather (no runtime indexing);
// bn-prep math inlined into consumer kernels (no tiny-launch bubbles);
// 4-replica stats atomics.
//
// Pipeline (6 launches):
//   k_prep    zero stats region
//   k_layer1  MFMA 16x16x32: h1 = W1|x_m-x_n|+b1 -> bufA + stats1
//   k_stats2  read h1, inline bn1, d = W2*act1 -> raw2 moments (no write)
//   k_fuse3   read h1, inline bn1+bn2, act2 -> h3 = W3*act2+b3 -> bufB+stats3
//   k_stats4  read h3, inline bn3, h4 = W4*act3+b4 -> stats4 (no write)
//   k_last    read h3, inline bn3+bn4-fold, -> out (fp32)
//
// ws layout (floats), all stats 4-replica:
//   [0..128)    stats1  4 x (sum16|ssq16)
//   [128..256)  raw2    4 x (S16|Q16)  of d = h2_pre - b2
//   [256..320)  stats3  4 x (sum8|ssq8)
//   [320..384)  stats4  4 x (sum8|ssq8)
//   byte 8192:             bufA h1: NN*16 bf16 = 75,497,472 B
//   byte 8192+75497472:    bufB h3: NN*8  bf16 = 37,748,736 B
// ---------------------------------------------------------------------------

#define NPTS 1536
#define NN   2359296u
static constexpr float FNN   = 2359296.0f;
static constexpr float EPS   = 1e-5f;
static constexpr float SLOPE = 0.01f;
static constexpr float INV_M = 1.0f / 2359296.0f;

typedef __attribute__((ext_vector_type(8))) short bf16x8;
typedef __attribute__((ext_vector_type(4))) float f32x4;
union frag8 { int4 i; bf16x8 v; };

__device__ __forceinline__ float bflo(unsigned u) {
    return __builtin_bit_cast(float, u << 16);
}
__device__ __forceinline__ float bfhi(unsigned u) {
    return __builtin_bit_cast(float, u & 0xffff0000u);
}
__device__ __forceinline__ unsigned short f2bf(float f) {   // RNE
    unsigned u = __builtin_bit_cast(unsigned, f);
    u += 0x7fffu + ((u >> 16) & 1u);
    return (unsigned short)(u >> 16);
}
__device__ __forceinline__ unsigned pack2(float lo, float hi) {
    return (unsigned)f2bf(lo) | ((unsigned)f2bf(hi) << 16);
}
__device__ __forceinline__ unsigned packtr(float lo, float hi) { // trunc
    unsigned a = __builtin_bit_cast(unsigned, lo);
    unsigned b = __builtin_bit_cast(unsigned, hi);
    return (a >> 16) | (b & 0xffff0000u);
}
__device__ __forceinline__ float lrelu(float t) {
    return fmaxf(t, t * SLOPE);
}

// inline bn over 16 channels from 4-replica stats (stride 32)
__device__ __forceinline__ void bn16_inline(
        const float* __restrict__ stats, const float* __restrict__ g,
        const float* __restrict__ be, float* sc, float* sh) {
#pragma unroll
    for (int c = 0; c < 16; c++) {
        float S = stats[c] + stats[32 + c] + stats[64 + c] + stats[96 + c];
        float Q = stats[16 + c] + stats[48 + c] + stats[80 + c] +
                  stats[112 + c];
        float mu  = S * INV_M;
        float var = fmaf(-mu, mu, Q * INV_M);
        float s   = g[c] * rsqrtf(var + EPS);
        sc[c] = s;
        sh[c] = fmaf(-mu, s, be[c]);
    }
}
// inline bn over 8 channels from 4-replica stats (stride 16)
__device__ __forceinline__ void bn8_inline(
        const float* __restrict__ stats, const float* __restrict__ g,
        const float* __restrict__ be, float* sc, float* sh) {
#pragma unroll
    for (int c = 0; c < 8; c++) {
        float S = stats[c] + stats[16 + c] + stats[32 + c] + stats[48 + c];
        float Q = stats[8 + c] + stats[24 + c] + stats[40 + c] +
                  stats[56 + c];
        float mu  = S * INV_M;
        float var = fmaf(-mu, mu, Q * INV_M);
        float s   = g[c] * rsqrtf(var + EPS);
        sc[c] = s;
        sh[c] = fmaf(-mu, s, be[c]);
    }
}

// --------------------------------------------------------------------------
__global__ __launch_bounds__(256) void k_prep(float* __restrict__ ws) {
    int t = threadIdx.x;
    if (t < 384) { ws[t] = 0.0f; }
    if (t < 128) { ws[256 + t] = 0.0f; }
}

// --------------------------------------------------------------------------
// Layer 1 (MFMA 16x16x32): h1[n,m,o] = b1[o] + sum_c W1[o,c]*|x[m,c]-x[n,c]|
__global__ __launch_bounds__(256) void k_layer1(
        const float* __restrict__ x, const float* __restrict__ W1,
        const float* __restrict__ b1, unsigned short* __restrict__ outb,
        float* __restrict__ stats) {
    int lane = threadIdx.x & 63;
    int wv   = threadIdx.x >> 6;
    int gid  = blockIdx.x * 4 + wv;
    int mt   = gid % 96;
    int nc   = gid / 96;          // 0..95
    int o    = lane & 15;
    int quad = lane >> 4;
    int cb   = quad * 8;

    const float* wr = W1 + o * 64 + cb;
    float4 w0 = *(const float4*)(wr);
    float4 w1 = *(const float4*)(wr + 4);
    float4 w2 = *(const float4*)(wr + 32);
    float4 w3 = *(const float4*)(wr + 36);
    frag8 fb1, fb2;
    fb1.i = make_int4(pack2(w0.x, w0.y), pack2(w0.z, w0.w),
                      pack2(w1.x, w1.y), pack2(w1.z, w1.w));
    fb2.i = make_int4(pack2(w2.x, w2.y), pack2(w2.z, w2.w),
                      pack2(w3.x, w3.y), pack2(w3.z, w3.w));

    const float* xr = x + (mt * 16 + o) * 64 + cb;
    float4 xa0 = *(const float4*)(xr);
    float4 xa1 = *(const float4*)(xr + 4);
    float4 xa2 = *(const float4*)(xr + 32);
    float4 xa3 = *(const float4*)(xr + 36);

    float bias = b1[o];
    float lsum = 0.f, lssq = 0.f;
    unsigned mrow = mt * 16 + quad * 4;

    int n0 = nc * 16;
    const float* xp = x + (size_t)n0 * 64 + cb;
    float4 uA0 = *(const float4*)(xp);
    float4 uA1 = *(const float4*)(xp + 4);
    float4 uA2 = *(const float4*)(xp + 32);
    float4 uA3 = *(const float4*)(xp + 36);
    const float* xq = x + (size_t)(n0 + 1) * 64 + cb;
    float4 uB0 = *(const float4*)(xq);
    float4 uB1 = *(const float4*)(xq + 4);
    float4 uB2 = *(const float4*)(xq + 32);
    float4 uB3 = *(const float4*)(xq + 36);

    auto body = [&](int n, float4& u0, float4& u1, float4& u2, float4& u3,
                    int pf) {
        frag8 fa1, fa2;
        fa1.i = make_int4(
            packtr(fabsf(xa0.x - u0.x), fabsf(xa0.y - u0.y)),
            packtr(fabsf(xa0.z - u0.z), fabsf(xa0.w - u0.w)),
            packtr(fabsf(xa1.x - u1.x), fabsf(xa1.y - u1.y)),
            packtr(fabsf(xa1.z - u1.z), fabsf(xa1.w - u1.w)));
        fa2.i = make_int4(
            packtr(fabsf(xa2.x - u2.x), fabsf(xa2.y - u2.y)),
            packtr(fabsf(xa2.z - u2.z), fabsf(xa2.w - u2.w)),
            packtr(fabsf(xa3.x - u3.x), fabsf(xa3.y - u3.y)),
            packtr(fabsf(xa3.z - u3.z), fabsf(xa3.w - u3.w)));
        const float* xf = x + (size_t)pf * 64 + cb;
        u0 = *(const float4*)(xf);
        u1 = *(const float4*)(xf + 4);
        u2 = *(const float4*)(xf + 32);
        u3 = *(const float4*)(xf + 36);
        f32x4 acc = {bias, bias, bias, bias};
        acc = __builtin_amdgcn_mfma_f32_16x16x32_bf16(fa1.v, fb1.v, acc, 0, 0, 0);
        acc = __builtin_amdgcn_mfma_f32_16x16x32_bf16(fa2.v, fb2.v, acc, 0, 0, 0);
        size_t base = ((size_t)n * NPTS + mrow) * 16 + o;
#pragma unroll
        for (int r = 0; r < 4; r++) {
            float v = acc[r];
            lsum += v;
            lssq = fmaf(v, v, lssq);
            outb[base + (unsigned)r * 16u] = f2bf(v);
        }
    };

#pragma unroll 1
    for (int i = 0; i < 16; i += 2) {
        int pfA = n0 + ((i + 2 < 16) ? i + 2 : 15);
        int pfB = n0 + ((i + 3 < 16) ? i + 3 : 15);
        body(n0 + i,     uA0, uA1, uA2, uA3, pfA);
        body(n0 + i + 1, uB0, uB1, uB2, uB3, pfB);
    }

    lsum += __shfl_xor(lsum, 16); lssq += __shfl_xor(lssq, 16);
    lsum += __shfl_xor(lsum, 32); lssq += __shfl_xor(lssq, 32);
    __shared__ float red[4][32];
    if (quad == 0) { red[wv][o] = lsum; red[wv][16 + o] = lssq; }
    __syncthreads();
    if (threadIdx.x < 32) {
        float v = red[0][threadIdx.x] + red[1][threadIdx.x] +
                  red[2][threadIdx.x] + red[3][threadIdx.x];
        atomicAdd(stats + (blockIdx.x & 3) * 32 + threadIdx.x, v);
    }
}

// --------------------------------------------------------------------------
// stats2: read h1, inline bn1, act1, d = W2*act1 (no b2) -> raw2 moments.
// og = tid&3 owns out-ch og*4..og*4+3 (64 weight floats hoisted).
__global__ __launch_bounds__(256) void k_stats2(
        const unsigned short* __restrict__ h1,
        const float* __restrict__ stats1, const float* __restrict__ g1,
        const float* __restrict__ be1, const float* __restrict__ W2,
        float* __restrict__ raw2) {
    int tid = threadIdx.x;
    int og  = tid & 3;

    float sc[16], sh[16];
    bn16_inline(stats1, g1, be1, sc, sh);

    float w[4][16];
#pragma unroll
    for (int j = 0; j < 4; j++) {
        const float* wr = W2 + (og * 4 + j) * 16;
#pragma unroll
        for (int q = 0; q < 4; q++) {
            float4 v = *(const float4*)(wr + q * 4);
            w[j][q*4+0] = v.x; w[j][q*4+1] = v.y;
            w[j][q*4+2] = v.z; w[j][q*4+3] = v.w;
        }
    }
    float sum[4] = {0.f, 0.f, 0.f, 0.f}, ssq[4] = {0.f, 0.f, 0.f, 0.f};

    size_t p0 = (size_t)blockIdx.x * 1152 + (tid >> 2);
    const uint4* src = (const uint4*)h1 + p0 * 2;
    uint4 va = src[0], vb = src[1];
#pragma unroll 1
    for (int it = 0; it < 18; it++) {
        int itn = (it + 1 < 18) ? it + 1 : 17;
        const uint4* s2 = src + (size_t)itn * 128;
        uint4 na = s2[0], nb = s2[1];
        float a[16];
        a[0] = bflo(va.x); a[1] = bfhi(va.x); a[2] = bflo(va.y); a[3] = bfhi(va.y);
        a[4] = bflo(va.z); a[5] = bfhi(va.z); a[6] = bflo(va.w); a[7] = bfhi(va.w);
        a[8] = bflo(vb.x); a[9] = bfhi(vb.x); a[10]= bflo(vb.y); a[11]= bfhi(vb.y);
        a[12]= bflo(vb.z); a[13]= bfhi(vb.z); a[14]= bflo(vb.w); a[15]= bfhi(vb.w);
#pragma unroll
        for (int c = 0; c < 16; c++)
            a[c] = lrelu(fmaf(a[c], sc[c], sh[c]));
        float d[4] = {0.f, 0.f, 0.f, 0.f};
#pragma unroll
        for (int c = 0; c < 16; c++) {
#pragma unroll
            for (int j = 0; j < 4; j++)
                d[j] = fmaf(a[c], w[j][c], d[j]);
        }
#pragma unroll
        for (int j = 0; j < 4; j++) {
            sum[j] += d[j];
            ssq[j] = fmaf(d[j], d[j], ssq[j]);
        }
        va = na; vb = nb;
    }
    // reduce across lanes sharing og (xor 4,8,16,32), then LDS, then atomics
#pragma unroll
    for (int off = 4; off < 64; off <<= 1) {
#pragma unroll
        for (int j = 0; j < 4; j++) {
            sum[j] += __shfl_xor(sum[j], off);
            ssq[j] += __shfl_xor(ssq[j], off);
        }
    }
    __shared__ float red[4][32];
    int wv = tid >> 6, lane = tid & 63;
    if (lane < 4) {
#pragma unroll
        for (int j = 0; j < 4; j++) {
            red[wv][og * 4 + j]      = sum[j];
            red[wv][16 + og * 4 + j] = ssq[j];
        }
    }
    __syncthreads();
    if (tid < 32) {
        float v = red[0][tid] + red[1][tid] + red[2][tid] + red[3][tid];
        atomicAdd(raw2 + (blockIdx.x & 3) * 32 + tid, v);
    }
}

// --------------------------------------------------------------------------
// fuse3: read h1, inline bn1 + bn2(raw2,b2-fold), act1 -> d -> act2
// -> quad shfl exchange -> h3 = W3*act2 + b3 -> bufB + stats3.
__global__ __launch_bounds__(256) void k_fuse3(
        const unsigned short* __restrict__ h1, unsigned* __restrict__ outb,
        const float* __restrict__ stats1, const float* __restrict__ g1,
        const float* __restrict__ be1, const float* __restrict__ W2,
        const float* __restrict__ raw2, const float* __restrict__ g2,
        const float* __restrict__ be2, const float* __restrict__ b2,
        const float* __restrict__ W3, const float* __restrict__ b3,
        float* __restrict__ stats3) {
    int tid = threadIdx.x;
    int og  = tid & 3;

    float sc[16], sh[16];
    bn16_inline(stats1, g1, be1, sc, sh);

    // bn2 for own 4 channels (fold b2): act2 = lrelu(d*sc2 + sh2)
    float sc2[4], sh2[4];
#pragma unroll
    for (int j = 0; j < 4; j++) {
        int c = og * 4 + j;
        float S = raw2[c] + raw2[32 + c] + raw2[64 + c] + raw2[96 + c];
        float Q = raw2[16 + c] + raw2[48 + c] + raw2[80 + c] + raw2[112 + c];
        float bc = b2[c];
        float sm = S + FNN * bc;
        float sq = Q + 2.0f * bc * S + FNN * bc * bc;
        float mu  = sm * INV_M;
        float var = fmaf(-mu, mu, sq * INV_M);
        float s   = g2[c] * rsqrtf(var + EPS);
        float shv = fmaf(-mu, s, be2[c]);
        sc2[j] = s;
        sh2[j] = fmaf(s, bc, shv);
    }

    float w[4][16];           // stage-1 W2 slice
#pragma unroll
    for (int j = 0; j < 4; j++) {
        const float* wr = W2 + (og * 4 + j) * 16;
#pragma unroll
        for (int q = 0; q < 4; q++) {
            float4 v = *(const float4*)(wr + q * 4);
            w[j][q*4+0] = v.x; w[j][q*4+1] = v.y;
            w[j][q*4+2] = v.z; w[j][q*4+3] = v.w;
        }
    }
    // stage-2 W3 slice in xor order: wl[r][xm][j] = W3[og*2+r][(og^xm)*4+j]
    float wl[2][4][4];
#pragma unroll
    for (int r2 = 0; r2 < 2; r2++)
#pragma unroll
        for (int xm = 0; xm < 4; xm++) {
            const float* wr = W3 + (og * 2 + r2) * 16 + ((og ^ xm) * 4);
            float4 v = *(const float4*)wr;
            wl[r2][xm][0] = v.x; wl[r2][xm][1] = v.y;
            wl[r2][xm][2] = v.z; wl[r2][xm][3] = v.w;
        }
    float b3a = b3[og * 2], b3b = b3[og * 2 + 1];

    float sum2[2] = {0.f, 0.f}, ssq2[2] = {0.f, 0.f};

    size_t p0 = (size_t)blockIdx.x * 1152 + (tid >> 2);
    const uint4* src = (const uint4*)h1 + p0 * 2;
    uint4 va = src[0], vb = src[1];
#pragma unroll 1
    for (int it = 0; it < 18; it++) {
        int itn = (it + 1 < 18) ? it + 1 : 17;
        const uint4* s2 = src + (size_t)itn * 128;
        uint4 na = s2[0], nb = s2[1];
        float a[16];
        a[0] = bflo(va.x); a[1] = bfhi(va.x); a[2] = bflo(va.y); a[3] = bfhi(va.y);
        a[4] = bflo(va.z); a[5] = bfhi(va.z); a[6] = bflo(va.w); a[7] = bfhi(va.w);
        a[8] = bflo(vb.x); a[9] = bfhi(vb.x); a[10]= bflo(vb.y); a[11]= bfhi(vb.y);
        a[12]= bflo(vb.z); a[13]= bfhi(vb.z); a[14]= bflo(vb.w); a[15]= bfhi(vb.w);
#pragma unroll
        for (int c = 0; c < 16; c++)
            a[c] = lrelu(fmaf(a[c], sc[c], sh[c]));
        float t[4] = {0.f, 0.f, 0.f, 0.f};
#pragma unroll
        for (int c = 0; c < 16; c++) {
#pragma unroll
            for (int j = 0; j < 4; j++)
                t[j] = fmaf(a[c], w[j][c], t[j]);
        }
#pragma unroll
        for (int j = 0; j < 4; j++)
            t[j] = lrelu(fmaf(t[j], sc2[j], sh2[j]));
        // stage 2: own group + 3 shfl partners
        float h3a = b3a, h3b = b3b;
#pragma unroll
        for (int j = 0; j < 4; j++) {
            h3a = fmaf(t[j], wl[0][0][j], h3a);
            h3b = fmaf(t[j], wl[1][0][j], h3b);
        }
#pragma unroll
        for (int xm = 1; xm < 4; xm++) {
#pragma unroll
            for (int j = 0; j < 4; j++) {
                float v = __shfl_xor(t[j], xm);
                h3a = fmaf(v, wl[0][xm][j], h3a);
                h3b = fmaf(v, wl[1][xm][j], h3b);
            }
        }
        sum2[0] += h3a; ssq2[0] = fmaf(h3a, h3a, ssq2[0]);
        sum2[1] += h3b; ssq2[1] = fmaf(h3b, h3b, ssq2[1]);
        size_t pos = p0 + (size_t)it * 64;
        outb[pos * 4 + og] = pack2(h3a, h3b);
        va = na; vb = nb;
    }
#pragma unroll
    for (int off = 4; off < 64; off <<= 1) {
#pragma unroll
        for (int r2 = 0; r2 < 2; r2++) {
            sum2[r2] += __shfl_xor(sum2[r2], off);
            ssq2[r2] += __shfl_xor(ssq2[r2], off);
        }
    }
    __shared__ float red[4][16];
    int wv = tid >> 6, lane = tid & 63;
    if (lane < 4) {
#pragma unroll
        for (int r2 = 0; r2 < 2; r2++) {
            red[wv][og * 2 + r2]     = sum2[r2];
            red[wv][8 + og * 2 + r2] = ssq2[r2];
        }
    }
    __syncthreads();
    if (tid < 16) {
        float v = red[0][tid] + red[1][tid] + red[2][tid] + red[3][tid];
        atomicAdd(stats3 + (blockIdx.x & 3) * 16 + tid, v);
    }
}

// --------------------------------------------------------------------------
// stats4: read h3, inline bn3, act3, h4 = W4*act3 + b4 -> stats4.
// og1 = tid&1 owns out-ch og1*4..+3 (32 weight floats).
__global__ __launch_bounds__(256) void k_stats4(
        const unsigned short* __restrict__ h3,
        const float* __restrict__ stats3, const float* __restrict__ g3,
        const float* __restrict__ be3, const float* __restrict__ W4,
        const float* __restrict__ b4, float* __restrict__ stats4) {
    int tid = threadIdx.x;
    int og1 = tid & 1;

    float sc[8], sh[8];
    bn8_inline(stats3, g3, be3, sc, sh);

    float w[4][8];
#pragma unroll
    for (int j = 0; j < 4; j++) {
        const float* wr = W4 + (og1 * 4 + j) * 8;
        float4 v0 = *(const float4*)(wr);
        float4 v1 = *(const float4*)(wr + 4);
        w[j][0] = v0.x; w[j][1] = v0.y; w[j][2] = v0.z; w[j][3] = v0.w;
        w[j][4] = v1.x; w[j][5] = v1.y; w[j][6] = v1.z; w[j][7] = v1.w;
    }
    float bi[4];
#pragma unroll
    for (int j = 0; j < 4; j++) bi[j] = b4[og1 * 4 + j];

    float sum[4] = {0.f, 0.f, 0.f, 0.f}, ssq[4] = {0.f, 0.f, 0.f, 0.f};

    size_t p0 = (size_t)blockIdx.x * 1152 + (tid >> 1);
    const uint4* src = (const uint4*)h3 + p0;
    uint4 va = src[0];
#pragma unroll 1
    for (int it = 0; it < 9; it++) {
        int itn = (it + 1 < 9) ? it + 1 : 8;
        uint4 na = src[(size_t)itn * 128];
        float a[8];
        a[0] = bflo(va.x); a[1] = bfhi(va.x); a[2] = bflo(va.y); a[3] = bfhi(va.y);
        a[4] = bflo(va.z); a[5] = bfhi(va.z); a[6] = bflo(va.w); a[7] = bfhi(va.w);
#pragma unroll
        for (int c = 0; c < 8; c++)
            a[c] = lrelu(fmaf(a[c], sc[c], sh[c]));
        float d[4] = {bi[0], bi[1], bi[2], bi[3]};
#pragma unroll
        for (int c = 0; c < 8; c++) {
#pragma unroll
            for (int j = 0; j < 4; j++)
                d[j] = fmaf(a[c], w[j][c], d[j]);
        }
#pragma unroll
        for (int j = 0; j < 4; j++) {
            sum[j] += d[j];
            ssq[j] = fmaf(d[j], d[j], ssq[j]);
        }
        va = na;
    }
#pragma unroll
    for (int off = 2; off < 64; off <<= 1) {
#pragma unroll
        for (int j = 0; j < 4; j++) {
            sum[j] += __shfl_xor(sum[j], off);
            ssq[j] += __shfl_xor(ssq[j], off);
        }
    }
    __shared__ float red[4][16];
    int wv = tid >> 6, lane = tid & 63;
    if (lane < 2) {
#pragma unroll
        for (int j = 0; j < 4; j++) {
            red[wv][og1 * 4 + j]     = sum[j];
            red[wv][8 + og1 * 4 + j] = ssq[j];
        }
    }
    __syncthreads();
    if (tid < 16) {
        float v = red[0][tid] + red[1][tid] + red[2][tid] + red[3][tid];
        atomicAdd(stats4 + (blockIdx.x & 3) * 16 + tid, v);
    }
}

// --------------------------------------------------------------------------
// last: read h3, inline bn3 + bn4-folded W4, -> out fp32. 4 pos/thread.
__global__ __launch_bounds__(256) void k_last(
        const unsigned short* __restrict__ h3,
        const float* __restrict__ stats3, const float* __restrict__ g3,
        const float* __restrict__ be3, const float* __restrict__ stats4,
        const float* __restrict__ g4, const float* __restrict__ be4,
        const float* __restrict__ W4, const float* __restrict__ b4,
        const float* __restrict__ W5, const float* __restrict__ b5,
        float* __restrict__ out) {
    int tid = threadIdx.x;

    float sc3[8], sh3[8];
    bn8_inline(stats3, g3, be3, sc3, sh3);

    // fold bn4 into W4: w4f[o][c] = sc4[o]*W4[o][c]; b4f = sc4*b4 + sh4
    float w4f[8][8], b4f[8], w5[8];
#pragma unroll
    for (int o = 0; o < 8; o++) {
        float S = stats4[o] + stats4[16 + o] + stats4[32 + o] + stats4[48 + o];
        float Q = stats4[8 + o] + stats4[24 + o] + stats4[40 + o] +
                  stats4[56 + o];
        float mu  = S * INV_M;
        float var = fmaf(-mu, mu, Q * INV_M);
        float s   = g4[o] * rsqrtf(var + EPS);
        float shv = fmaf(-mu, s, be4[o]);
        b4f[o] = fmaf(s, b4[o], shv);
        const float* wr = W4 + o * 8;
        float4 v0 = *(const float4*)(wr);
        float4 v1 = *(const float4*)(wr + 4);
        w4f[o][0] = s * v0.x; w4f[o][1] = s * v0.y;
        w4f[o][2] = s * v0.z; w4f[o][3] = s * v0.w;
        w4f[o][4] = s * v1.x; w4f[o][5] = s * v1.y;
        w4f[o][6] = s * v1.z; w4f[o][7] = s * v1.w;
        w5[o] = W5[o];
    }
    float b5v = b5[0];

    size_t p0 = (size_t)blockIdx.x * 1024 + tid;
    const uint4* src = (const uint4*)h3 + p0;
    uint4 va = src[0];
#pragma unroll 1
    for (int it = 0; it < 4; it++) {
        int itn = (it + 1 < 4) ? it + 1 : 3;
        uint4 na = src[(size_t)itn * 256];
        float a[8];
        a[0] = bflo(va.x); a[1] = bfhi(va.x); a[2] = bflo(va.y); a[3] = bfhi(va.y);
        a[4] = bflo(va.z); a[5] = bfhi(va.z); a[6] = bflo(va.w); a[7] = bfhi(va.w);
#pragma unroll
        for (int c = 0; c < 8; c++)
            a[c] = lrelu(fmaf(a[c], sc3[c], sh3[c]));
        float acc = b5v;
#pragma unroll
        for (int o = 0; o < 8; o++) {
            float h = b4f[o];
#pragma unroll
            for (int c = 0; c < 8; c++)
                h = fmaf(a[c], w4f[o][c], h);
            acc = fmaf(lrelu(h), w5[o], acc);
        }
        out[p0 + (size_t)it * 256] = acc;
        va = na;
    }
}

// --------------------------------------------------------------------------
extern "C" void kernel_launch(void* const* d_in, const int* in_sizes, int n_in,
                              void* d_out, int out_size, void* d_ws,
                              size_t ws_size, hipStream_t stream) {
    const float* x   = (const float*)d_in[0];
    const float* W1  = (const float*)d_in[1];
    const float* b1  = (const float*)d_in[2];
    const float* g1  = (const float*)d_in[3];
    const float* be1 = (const float*)d_in[4];
    const float* W2  = (const float*)d_in[5];
    const float* b2  = (const float*)d_in[6];
    const float* g2  = (const float*)d_in[7];
    const float* be2 = (const float*)d_in[8];
    const float* W3  = (const float*)d_in[9];
    const float* b3  = (const float*)d_in[10];
    const float* g3  = (const float*)d_in[11];
    const float* be3 = (const float*)d_in[12];
    const float* W4  = (const float*)d_in[13];
    const float* b4  = (const float*)d_in[14];
    const float* g4  = (const float*)d_in[15];
    const float* be4 = (const float*)d_in[16];
    const float* W5  = (const float*)d_in[17];
    const float* b5  = (const float*)d_in[18];

    float* ws     = (float*)d_ws;
    float* stats1 = ws + 0;     // 4 x 32
    float* raw2   = ws + 128;   // 4 x 32
    float* stats3 = ws + 256;   // 4 x 16
    float* stats4 = ws + 320;   // 4 x 16
    unsigned short* bufA = (unsigned short*)((char*)d_ws + 8192);
    unsigned short* bufB =
        (unsigned short*)((char*)d_ws + 8192 + (size_t)NN * 32u);

    k_prep<<<1, 384, 0, stream>>>(ws);
    k_layer1<<<2304, 256, 0, stream>>>(x, W1, b1, bufA, stats1);
    k_stats2<<<2048, 256, 0, stream>>>(bufA, stats1, g1, be1, W2, raw2);
    k_fuse3<<<2048, 256, 0, stream>>>(bufA, (unsigned*)bufB, stats1, g1, be1,
                                      W2, raw2, g2, be2, b2, W3, b3, stats3);
    k_stats4<<<2048, 256, 0, stream>>>(bufB, stats3, g3, be3, W4, b4, stats4);
    k_last<<<2304, 256, 0, stream>>>(bufB, stats3, g3, be3, stats4, g4, be4,
                                     W4, b4, W5, b5, (float*)d_out);
}

// Round 6
// 237.703 us; speedup vs baseline: 5.6028x; 1.2061x over previous
//
#include <hip/hip_runtime.h>
#include <stdint.h>

// ---------------------------------------------------------------------------
// AdjCompute R6.
// Lessons: R3 in-loop weight loads = 7x VALU bloat; R4 per-iter LDS+waitcnt
// = latency collapse; R5 VALU mids OK but fuse3 ~760 lane-ops/pos and
// layer1 write-bound at 1.06 TB/s (2B scattered stores).
// R6: (1) layer1 MFMA operand swap -> D=[o][m] -> coalesced uint2 stores;
// (2) stats2/fuse3 on mfma_f32_16x16x32_bf16 (verified intrinsic), K=16
// zero-padded: act1 in B-frag (quads 0,1 real / 2,3 zero), W2/W3 in A-frags;
// fuse3 chains D1 -> act2 -> shfl repack -> MFMA2, no LDS, no barriers.
//
// Pipeline (6 launches):
//   k_prep    zero stats region
//   k_layer1  MFMA: h1 = W1|x_m-x_n|+b1 -> bufA[pos][16ch] + stats1
//   k_stats2  MFMA: moments of d = W2*act1 (no write)
//   k_fuse3   MFMA x2: act1 -> d -> act2 -> h3 = W3*act2+b3 -> bufB + stats3
//   k_stats4  VALU: stats of h4 = W4*act3+b4 (no write)
//   k_last    VALU: h3 -> act3 -> h4 -> act4 -> out (fp32)
//
// ws layout (floats), all stats 4-replica:
//   [0..128)    stats1  4 x (sum16|ssq16)
//   [128..256)  raw2    4 x (S16|Q16)  of d = h2_pre - b2
//   [256..320)  stats3  4 x (sum8|ssq8)
//   [320..384)  stats4  4 x (sum8|ssq8)
//   byte 8192:             bufA h1: NN*16 bf16 = 75,497,472 B
//   byte 8192+75497472:    bufB h3: NN*8  bf16 = 37,748,736 B
//
// MFMA 16x16x32 layouts [m89/m91, verified in R2-R5]:
//   A[i=lane&15][k=quad*8+j], B[k=quad*8+j][col=lane&15],
//   D: col=lane&15, row=quad*4+reg.
// ---------------------------------------------------------------------------

#define NPTS 1536
#define NN   2359296u
static constexpr float FNN   = 2359296.0f;
static constexpr float EPS   = 1e-5f;
static constexpr float SLOPE = 0.01f;
static constexpr float INV_M = 1.0f / 2359296.0f;

typedef __attribute__((ext_vector_type(8))) short bf16x8;
typedef __attribute__((ext_vector_type(4))) float f32x4;
union frag8 { int4 i; bf16x8 v; };

__device__ __forceinline__ float bflo(unsigned u) {
    return __builtin_bit_cast(float, u << 16);
}
__device__ __forceinline__ float bfhi(unsigned u) {
    return __builtin_bit_cast(float, u & 0xffff0000u);
}
__device__ __forceinline__ unsigned short f2bf(float f) {   // RNE
    unsigned u = __builtin_bit_cast(unsigned, f);
    u += 0x7fffu + ((u >> 16) & 1u);
    return (unsigned short)(u >> 16);
}
__device__ __forceinline__ unsigned pack2(float lo, float hi) {
    return (unsigned)f2bf(lo) | ((unsigned)f2bf(hi) << 16);
}
__device__ __forceinline__ unsigned packtr(float lo, float hi) { // trunc
    unsigned a = __builtin_bit_cast(unsigned, lo);
    unsigned b = __builtin_bit_cast(unsigned, hi);
    return (a >> 16) | (b & 0xffff0000u);
}
__device__ __forceinline__ float lrelu(float t) {
    return fmaxf(t, t * SLOPE);
}
__device__ __forceinline__ float4 ld4(const float* p) {
    return *(const float4*)p;
}

// bn over 8 channels from 4-replica 8ch stats (replica stride 16)
__device__ __forceinline__ void bn8_inline(
        const float* __restrict__ stats, const float* __restrict__ g,
        const float* __restrict__ be, float* sc, float* sh) {
#pragma unroll
    for (int c = 0; c < 8; c++) {
        float S = stats[c] + stats[16 + c] + stats[32 + c] + stats[48 + c];
        float Q = stats[8 + c] + stats[24 + c] + stats[40 + c] +
                  stats[56 + c];
        float mu  = S * INV_M;
        float var = fmaf(-mu, mu, Q * INV_M);
        float s   = g[c] * rsqrtf(var + EPS);
        sc[c] = s;
        sh[c] = fmaf(-mu, s, be[c]);
    }
}

// --------------------------------------------------------------------------
__global__ __launch_bounds__(256) void k_prep(float* __restrict__ ws) {
    int t = threadIdx.x;
    if (t < 384) ws[t] = 0.0f;
}

// --------------------------------------------------------------------------
// Layer 1: h1[pos=n*1536+m][o] = b1[o] + sum_c W1[o,c]*|x[m,c]-x[n,c]|
// MFMA with A=W1 (rows o), B=adj (cols m) -> D[o=quad*4+r][m=lane&15]
// -> coalesced uint2 store of 4 consecutive channels.
__global__ __launch_bounds__(256) void k_layer1(
        const float* __restrict__ x, const float* __restrict__ W1,
        const float* __restrict__ b1, unsigned short* __restrict__ outb,
        float* __restrict__ stats) {
    int tid  = threadIdx.x;
    int lane = tid & 63;
    int wv   = tid >> 6;
    int gid  = blockIdx.x * 4 + wv;
    int mt   = gid % 96;
    int nc   = gid / 96;          // 0..95
    int l15  = lane & 15;         // A row (o) for W1 frag; B col (m) for adj
    int quad = lane >> 4;
    int cb   = quad * 8;

    // A-frag: W1[o=l15][cb..cb+7] (+32 for 2nd mfma)
    const float* wr = W1 + l15 * 64 + cb;
    float4 w0 = ld4(wr);
    float4 w1 = ld4(wr + 4);
    float4 w2 = ld4(wr + 32);
    float4 w3 = ld4(wr + 36);
    frag8 fb1, fb2;
    fb1.i = make_int4(pack2(w0.x, w0.y), pack2(w0.z, w0.w),
                      pack2(w1.x, w1.y), pack2(w1.z, w1.w));
    fb2.i = make_int4(pack2(w2.x, w2.y), pack2(w2.z, w2.w),
                      pack2(w3.x, w3.y), pack2(w3.z, w3.w));

    // B-frag source: x row for this lane's position m = mt*16 + l15
    const float* xr = x + (mt * 16 + l15) * 64 + cb;
    float4 xa0 = ld4(xr);
    float4 xa1 = ld4(xr + 4);
    float4 xa2 = ld4(xr + 32);
    float4 xa3 = ld4(xr + 36);

    float4 b1v = ld4(b1 + quad * 4);   // bias for rows o = quad*4+r
    float lsum[4] = {0.f, 0.f, 0.f, 0.f};
    float lssq[4] = {0.f, 0.f, 0.f, 0.f};

    int n0 = nc * 16;
    const float* xp = x + (size_t)n0 * 64 + cb;
    float4 uA0 = ld4(xp);
    float4 uA1 = ld4(xp + 4);
    float4 uA2 = ld4(xp + 32);
    float4 uA3 = ld4(xp + 36);
    const float* xq = x + (size_t)(n0 + 1) * 64 + cb;
    float4 uB0 = ld4(xq);
    float4 uB1 = ld4(xq + 4);
    float4 uB2 = ld4(xq + 32);
    float4 uB3 = ld4(xq + 36);

    auto body = [&](int n, float4& u0, float4& u1, float4& u2, float4& u3,
                    int pf) {
        frag8 fa1, fa2;
        fa1.i = make_int4(
            packtr(fabsf(xa0.x - u0.x), fabsf(xa0.y - u0.y)),
            packtr(fabsf(xa0.z - u0.z), fabsf(xa0.w - u0.w)),
            packtr(fabsf(xa1.x - u1.x), fabsf(xa1.y - u1.y)),
            packtr(fabsf(xa1.z - u1.z), fabsf(xa1.w - u1.w)));
        fa2.i = make_int4(
            packtr(fabsf(xa2.x - u2.x), fabsf(xa2.y - u2.y)),
            packtr(fabsf(xa2.z - u2.z), fabsf(xa2.w - u2.w)),
            packtr(fabsf(xa3.x - u3.x), fabsf(xa3.y - u3.y)),
            packtr(fabsf(xa3.z - u3.z), fabsf(xa3.w - u3.w)));
        const float* xf = x + (size_t)pf * 64 + cb;
        u0 = ld4(xf);
        u1 = ld4(xf + 4);
        u2 = ld4(xf + 32);
        u3 = ld4(xf + 36);
        f32x4 acc = {b1v.x, b1v.y, b1v.z, b1v.w};
        // A = W1, B = adj  ->  D[o][m]
        acc = __builtin_amdgcn_mfma_f32_16x16x32_bf16(fb1.v, fa1.v, acc, 0, 0, 0);
        acc = __builtin_amdgcn_mfma_f32_16x16x32_bf16(fb2.v, fa2.v, acc, 0, 0, 0);
        size_t pos = (size_t)n * NPTS + mt * 16 + l15;
#pragma unroll
        for (int r = 0; r < 4; r++) {
            lsum[r] += acc[r];
            lssq[r] = fmaf(acc[r], acc[r], lssq[r]);
        }
        *(uint2*)(outb + pos * 16 + quad * 4) =
            make_uint2(pack2(acc[0], acc[1]), pack2(acc[2], acc[3]));
    };

#pragma unroll 1
    for (int i = 0; i < 16; i += 2) {
        int pfA = n0 + ((i + 2 < 16) ? i + 2 : 15);
        int pfB = n0 + ((i + 3 < 16) ? i + 3 : 15);
        body(n0 + i,     uA0, uA1, uA2, uA3, pfA);
        body(n0 + i + 1, uB0, uB1, uB2, uB3, pfB);
    }

    // reduce over positions (lane&15), channels live at quad*4+r
#pragma unroll
    for (int off = 1; off < 16; off <<= 1) {
#pragma unroll
        for (int r = 0; r < 4; r++) {
            lsum[r] += __shfl_xor(lsum[r], off);
            lssq[r] += __shfl_xor(lssq[r], off);
        }
    }
    __shared__ float red[4][32];
    if (l15 == 0) {
#pragma unroll
        for (int r = 0; r < 4; r++) {
            red[wv][quad * 4 + r]      = lsum[r];
            red[wv][16 + quad * 4 + r] = lssq[r];
        }
    }
    __syncthreads();
    if (tid < 32) {
        float v = red[0][tid] + red[1][tid] + red[2][tid] + red[3][tid];
        atomicAdd(stats + (blockIdx.x & 3) * 32 + tid, v);
    }
}

// --------------------------------------------------------------------------
// stats2: MFMA stage-1 only. B = act1 (quads 0,1 carry K=16; 2,3 zero),
// A = W2. D[o=quad*4+r][m=lane&15] -> raw moments of d (b2 excluded).
__global__ __launch_bounds__(256) void k_stats2(
        const unsigned short* __restrict__ h1,
        const float* __restrict__ stats1, const float* __restrict__ g1,
        const float* __restrict__ be1, const float* __restrict__ W2,
        float* __restrict__ raw2) {
    int tid  = threadIdx.x;
    int lane = tid & 63;
    int wv   = tid >> 6;
    int l15  = lane & 15;
    int quad = lane >> 4;
    int cq   = (quad & 1) * 8;    // input channel base (quads 2,3 mirror)
    int gid  = blockIdx.x * 4 + wv;

    float sc[8], sh[8];
#pragma unroll
    for (int j = 0; j < 8; j++) {
        int c = cq + j;
        float S = stats1[c] + stats1[32 + c] + stats1[64 + c] + stats1[96 + c];
        float Q = stats1[16 + c] + stats1[48 + c] + stats1[80 + c] +
                  stats1[112 + c];
        float mu  = S * INV_M;
        float var = fmaf(-mu, mu, Q * INV_M);
        float s   = g1[c] * rsqrtf(var + EPS);
        sc[j] = s;
        sh[j] = fmaf(-mu, s, be1[c]);
    }
    frag8 fw2; fw2.i = make_int4(0, 0, 0, 0);
    if (quad < 2) {
        const float* w = W2 + l15 * 16 + quad * 8;
        float4 wa = ld4(w), wb = ld4(w + 4);
        fw2.i = make_int4(pack2(wa.x, wa.y), pack2(wa.z, wa.w),
                          pack2(wb.x, wb.y), pack2(wb.z, wb.w));
    }

    float sum[4] = {0.f, 0.f, 0.f, 0.f}, ssq[4] = {0.f, 0.f, 0.f, 0.f};
    size_t tile0 = (size_t)gid * 18;
    const unsigned short* ptr = h1 + (tile0 * 16 + l15) * 16 + cq;
    uint4 va = make_uint4(0, 0, 0, 0);
    if (quad < 2) va = *(const uint4*)ptr;
#pragma unroll 1
    for (int it = 0; it < 18; it++) {
        uint4 nx = va;
        if (quad < 2 && it + 1 < 18)
            nx = *(const uint4*)(ptr + (size_t)(it + 1) * 256);
        frag8 fb; fb.i = make_int4(0, 0, 0, 0);
        if (quad < 2) {
            float a0 = bflo(va.x), a1 = bfhi(va.x);
            float a2 = bflo(va.y), a3 = bfhi(va.y);
            float a4 = bflo(va.z), a5 = bfhi(va.z);
            float a6 = bflo(va.w), a7 = bfhi(va.w);
            a0 = lrelu(fmaf(a0, sc[0], sh[0]));
            a1 = lrelu(fmaf(a1, sc[1], sh[1]));
            a2 = lrelu(fmaf(a2, sc[2], sh[2]));
            a3 = lrelu(fmaf(a3, sc[3], sh[3]));
            a4 = lrelu(fmaf(a4, sc[4], sh[4]));
            a5 = lrelu(fmaf(a5, sc[5], sh[5]));
            a6 = lrelu(fmaf(a6, sc[6], sh[6]));
            a7 = lrelu(fmaf(a7, sc[7], sh[7]));
            fb.i = make_int4(pack2(a0, a1), pack2(a2, a3),
                             pack2(a4, a5), pack2(a6, a7));
        }
        f32x4 z = {0.f, 0.f, 0.f, 0.f};
        f32x4 d = __builtin_amdgcn_mfma_f32_16x16x32_bf16(fw2.v, fb.v, z, 0, 0, 0);
#pragma unroll
        for (int r = 0; r < 4; r++) {
            sum[r] += d[r];
            ssq[r] = fmaf(d[r], d[r], ssq[r]);
        }
        va = nx;
    }
#pragma unroll
    for (int off = 1; off < 16; off <<= 1) {
#pragma unroll
        for (int r = 0; r < 4; r++) {
            sum[r] += __shfl_xor(sum[r], off);
            ssq[r] += __shfl_xor(ssq[r], off);
        }
    }
    __shared__ float red[4][32];
    if (l15 == 0) {
#pragma unroll
        for (int r = 0; r < 4; r++) {
            red[wv][quad * 4 + r]      = sum[r];
            red[wv][16 + quad * 4 + r] = ssq[r];
        }
    }
    __syncthreads();
    if (tid < 32) {
        float v = red[0][tid] + red[1][tid] + red[2][tid] + red[3][tid];
        atomicAdd(raw2 + (blockIdx.x & 3) * 32 + tid, v);
    }
}

// --------------------------------------------------------------------------
// fuse3: stage-1 MFMA (d = W2*act1) -> act2 on D regs -> shfl repack to
// B-layout -> stage-2 MFMA (A=W3) -> h3 + stats3. No LDS, no barriers.
__global__ __launch_bounds__(256) void k_fuse3(
        const unsigned short* __restrict__ h1,
        unsigned short* __restrict__ h3out,
        const float* __restrict__ stats1, const float* __restrict__ g1,
        const float* __restrict__ be1, const float* __restrict__ W2,
        const float* __restrict__ raw2, const float* __restrict__ g2,
        const float* __restrict__ be2, const float* __restrict__ b2,
        const float* __restrict__ W3, const float* __restrict__ b3,
        float* __restrict__ stats3) {
    int tid  = threadIdx.x;
    int lane = tid & 63;
    int wv   = tid >> 6;
    int l15  = lane & 15;
    int quad = lane >> 4;
    int cq   = (quad & 1) * 8;
    int gid  = blockIdx.x * 4 + wv;

    float sc[8], sh[8];
#pragma unroll
    for (int j = 0; j < 8; j++) {
        int c = cq + j;
        float S = stats1[c] + stats1[32 + c] + stats1[64 + c] + stats1[96 + c];
        float Q = stats1[16 + c] + stats1[48 + c] + stats1[80 + c] +
                  stats1[112 + c];
        float mu  = S * INV_M;
        float var = fmaf(-mu, mu, Q * INV_M);
        float s   = g1[c] * rsqrtf(var + EPS);
        sc[j] = s;
        sh[j] = fmaf(-mu, s, be1[c]);
    }
    // bn2 for this lane's D rows o = quad*4+r (b2 folded)
    float sc2[4], sh2[4];
#pragma unroll
    for (int r = 0; r < 4; r++) {
        int c = quad * 4 + r;
        float S = raw2[c] + raw2[32 + c] + raw2[64 + c] + raw2[96 + c];
        float Q = raw2[16 + c] + raw2[48 + c] + raw2[80 + c] + raw2[112 + c];
        float bc = b2[c];
        float sm = S + FNN * bc;
        float sq = Q + 2.0f * bc * S + FNN * bc * bc;
        float mu  = sm * INV_M;
        float var = fmaf(-mu, mu, sq * INV_M);
        float s   = g2[c] * rsqrtf(var + EPS);
        float shv = fmaf(-mu, s, be2[c]);
        sc2[r] = s;
        sh2[r] = fmaf(s, bc, shv);
    }
    frag8 fw2; fw2.i = make_int4(0, 0, 0, 0);
    if (quad < 2) {
        const float* w = W2 + l15 * 16 + quad * 8;
        float4 wa = ld4(w), wb = ld4(w + 4);
        fw2.i = make_int4(pack2(wa.x, wa.y), pack2(wa.z, wa.w),
                          pack2(wb.x, wb.y), pack2(wb.z, wb.w));
    }
    frag8 fw3; fw3.i = make_int4(0, 0, 0, 0);
    if (l15 < 8 && quad < 2) {
        const float* w = W3 + l15 * 16 + quad * 8;
        float4 wa = ld4(w), wb = ld4(w + 4);
        fw3.i = make_int4(pack2(wa.x, wa.y), pack2(wa.z, wa.w),
                          pack2(wb.x, wb.y), pack2(wb.z, wb.w));
    }
    float b3r[4];
#pragma unroll
    for (int r = 0; r < 4; r++) b3r[r] = b3[(quad & 1) * 4 + r];

    float sum3[4] = {0.f, 0.f, 0.f, 0.f}, ssq3[4] = {0.f, 0.f, 0.f, 0.f};
    size_t tile0 = (size_t)gid * 18;
    const unsigned short* ptr = h1 + (tile0 * 16 + l15) * 16 + cq;
    uint4 va = make_uint4(0, 0, 0, 0);
    if (quad < 2) va = *(const uint4*)ptr;
#pragma unroll 1
    for (int it = 0; it < 18; it++) {
        uint4 nx = va;
        if (quad < 2 && it + 1 < 18)
            nx = *(const uint4*)(ptr + (size_t)(it + 1) * 256);
        frag8 fb; fb.i = make_int4(0, 0, 0, 0);
        if (quad < 2) {
            float a0 = bflo(va.x), a1 = bfhi(va.x);
            float a2 = bflo(va.y), a3 = bfhi(va.y);
            float a4 = bflo(va.z), a5 = bfhi(va.z);
            float a6 = bflo(va.w), a7 = bfhi(va.w);
            a0 = lrelu(fmaf(a0, sc[0], sh[0]));
            a1 = lrelu(fmaf(a1, sc[1], sh[1]));
            a2 = lrelu(fmaf(a2, sc[2], sh[2]));
            a3 = lrelu(fmaf(a3, sc[3], sh[3]));
            a4 = lrelu(fmaf(a4, sc[4], sh[4]));
            a5 = lrelu(fmaf(a5, sc[5], sh[5]));
            a6 = lrelu(fmaf(a6, sc[6], sh[6]));
            a7 = lrelu(fmaf(a7, sc[7], sh[7]));
            fb.i = make_int4(pack2(a0, a1), pack2(a2, a3),
                             pack2(a4, a5), pack2(a6, a7));
        }
        f32x4 z = {0.f, 0.f, 0.f, 0.f};
        f32x4 d1 = __builtin_amdgcn_mfma_f32_16x16x32_bf16(fw2.v, fb.v, z, 0, 0, 0);
        float t0 = lrelu(fmaf(d1[0], sc2[0], sh2[0]));
        float t1 = lrelu(fmaf(d1[1], sc2[1], sh2[1]));
        float t2 = lrelu(fmaf(d1[2], sc2[2], sh2[2]));
        float t3 = lrelu(fmaf(d1[3], sc2[3], sh2[3]));
        unsigned pk0 = pack2(t0, t1), pk1 = pack2(t2, t3);
        // repack act2[o][m] into B-layout (k = quad*8+j):
        // quad q<2 needs rows q*8..q*8+7 = regs of lanes (m, 2q) and (m, 2q+1)
        int s0 = l15 + 32 * (quad & 1);
        unsigned e0 = (unsigned)__shfl((int)pk0, s0);
        unsigned e1 = (unsigned)__shfl((int)pk1, s0);
        unsigned e2 = (unsigned)__shfl((int)pk0, s0 + 16);
        unsigned e3 = (unsigned)__shfl((int)pk1, s0 + 16);
        frag8 fb2;
        fb2.i = (quad < 2) ? make_int4(e0, e1, e2, e3) : make_int4(0, 0, 0, 0);
        f32x4 d2 = __builtin_amdgcn_mfma_f32_16x16x32_bf16(fw3.v, fb2.v, z, 0, 0, 0);
        if (quad < 2) {
            float h0 = d2[0] + b3r[0];
            float h1v = d2[1] + b3r[1];
            float h2 = d2[2] + b3r[2];
            float h3v = d2[3] + b3r[3];
            sum3[0] += h0;  ssq3[0] = fmaf(h0, h0, ssq3[0]);
            sum3[1] += h1v; ssq3[1] = fmaf(h1v, h1v, ssq3[1]);
            sum3[2] += h2;  ssq3[2] = fmaf(h2, h2, ssq3[2]);
            sum3[3] += h3v; ssq3[3] = fmaf(h3v, h3v, ssq3[3]);
            size_t pos = (tile0 + it) * 16 + l15;
            *(uint2*)(h3out + pos * 8 + quad * 4) =
                make_uint2(pack2(h0, h1v), pack2(h2, h3v));
        }
        va = nx;
    }
#pragma unroll
    for (int off = 1; off < 16; off <<= 1) {
#pragma unroll
        for (int r = 0; r < 4; r++) {
            sum3[r] += __shfl_xor(sum3[r], off);
            ssq3[r] += __shfl_xor(ssq3[r], off);
        }
    }
    __shared__ float red[4][16];
    if (l15 == 0 && quad < 2) {
#pragma unroll
        for (int r = 0; r < 4; r++) {
            red[wv][quad * 4 + r]     = sum3[r];
            red[wv][8 + quad * 4 + r] = ssq3[r];
        }
    }
    __syncthreads();
    if (tid < 16) {
        float v = red[0][tid] + red[1][tid] + red[2][tid] + red[3][tid];
        atomicAdd(stats3 + (blockIdx.x & 3) * 16 + tid, v);
    }
}

// --------------------------------------------------------------------------
// stats4 (VALU, from R5): read h3, inline bn3, h4 = W4*act3 + b4 -> stats4.
__global__ __launch_bounds__(256) void k_stats4(
        const unsigned short* __restrict__ h3,
        const float* __restrict__ stats3, const float* __restrict__ g3,
        const float* __restrict__ be3, const float* __restrict__ W4,
        const float* __restrict__ b4, float* __restrict__ stats4) {
    int tid = threadIdx.x;
    int og1 = tid & 1;

    float sc[8], sh[8];
    bn8_inline(stats3, g3, be3, sc, sh);

    float w[4][8];
#pragma unroll
    for (int j = 0; j < 4; j++) {
        const float* wr = W4 + (og1 * 4 + j) * 8;
        float4 v0 = ld4(wr);
        float4 v1 = ld4(wr + 4);
        w[j][0] = v0.x; w[j][1] = v0.y; w[j][2] = v0.z; w[j][3] = v0.w;
        w[j][4] = v1.x; w[j][5] = v1.y; w[j][6] = v1.z; w[j][7] = v1.w;
    }
    float bi[4];
#pragma unroll
    for (int j = 0; j < 4; j++) bi[j] = b4[og1 * 4 + j];

    float sum[4] = {0.f, 0.f, 0.f, 0.f}, ssq[4] = {0.f, 0.f, 0.f, 0.f};

    size_t p0 = (size_t)blockIdx.x * 1152 + (tid >> 1);
    const uint4* src = (const uint4*)h3 + p0;
    uint4 va = src[0];
#pragma unroll 1
    for (int it = 0; it < 9; it++) {
        int itn = (it + 1 < 9) ? it + 1 : 8;
        uint4 na = src[(size_t)itn * 128];
        float a[8];
        a[0] = bflo(va.x); a[1] = bfhi(va.x); a[2] = bflo(va.y); a[3] = bfhi(va.y);
        a[4] = bflo(va.z); a[5] = bfhi(va.z); a[6] = bflo(va.w); a[7] = bfhi(va.w);
#pragma unroll
        for (int c = 0; c < 8; c++)
            a[c] = lrelu(fmaf(a[c], sc[c], sh[c]));
        float d[4] = {bi[0], bi[1], bi[2], bi[3]};
#pragma unroll
        for (int c = 0; c < 8; c++) {
#pragma unroll
            for (int j = 0; j < 4; j++)
                d[j] = fmaf(a[c], w[j][c], d[j]);
        }
#pragma unroll
        for (int j = 0; j < 4; j++) {
            sum[j] += d[j];
            ssq[j] = fmaf(d[j], d[j], ssq[j]);
        }
        va = na;
    }
#pragma unroll
    for (int off = 2; off < 64; off <<= 1) {
#pragma unroll
        for (int j = 0; j < 4; j++) {
            sum[j] += __shfl_xor(sum[j], off);
            ssq[j] += __shfl_xor(ssq[j], off);
        }
    }
    __shared__ float red[4][16];
    int wv = tid >> 6, lane = tid & 63;
    if (lane < 2) {
#pragma unroll
        for (int j = 0; j < 4; j++) {
            red[wv][og1 * 4 + j]     = sum[j];
            red[wv][8 + og1 * 4 + j] = ssq[j];
        }
    }
    __syncthreads();
    if (tid < 16) {
        float v = red[0][tid] + red[1][tid] + red[2][tid] + red[3][tid];
        atomicAdd(stats4 + (blockIdx.x & 3) * 16 + tid, v);
    }
}

// --------------------------------------------------------------------------
// last (VALU, from R5): h3 -> act3 -> h4 (bn4-folded W4) -> act4 -> out
__global__ __launch_bounds__(256) void k_last(
        const unsigned short* __restrict__ h3,
        const float* __restrict__ stats3, const float* __restrict__ g3,
        const float* __restrict__ be3, const float* __restrict__ stats4,
        const float* __restrict__ g4, const float* __restrict__ be4,
        const float* __restrict__ W4, const float* __restrict__ b4,
        const float* __restrict__ W5, const float* __restrict__ b5,
        float* __restrict__ out) {
    int tid = threadIdx.x;

    float sc3[8], sh3[8];
    bn8_inline(stats3, g3, be3, sc3, sh3);

    float w4f[8][8], b4f[8], w5[8];
#pragma unroll
    for (int o = 0; o < 8; o++) {
        float S = stats4[o] + stats4[16 + o] + stats4[32 + o] + stats4[48 + o];
        float Q = stats4[8 + o] + stats4[24 + o] + stats4[40 + o] +
                  stats4[56 + o];
        float mu  = S * INV_M;
        float var = fmaf(-mu, mu, Q * INV_M);
        float s   = g4[o] * rsqrtf(var + EPS);
        float shv = fmaf(-mu, s, be4[o]);
        b4f[o] = fmaf(s, b4[o], shv);
        const float* wr = W4 + o * 8;
        float4 v0 = ld4(wr);
        float4 v1 = ld4(wr + 4);
        w4f[o][0] = s * v0.x; w4f[o][1] = s * v0.y;
        w4f[o][2] = s * v0.z; w4f[o][3] = s * v0.w;
        w4f[o][4] = s * v1.x; w4f[o][5] = s * v1.y;
        w4f[o][6] = s * v1.z; w4f[o][7] = s * v1.w;
        w5[o] = W5[o];
    }
    float b5v = b5[0];

    size_t p0 = (size_t)blockIdx.x * 1024 + tid;
    const uint4* src = (const uint4*)h3 + p0;
    uint4 va = src[0];
#pragma unroll 1
    for (int it = 0; it < 4; it++) {
        int itn = (it + 1 < 4) ? it + 1 : 3;
        uint4 na = src[(size_t)itn * 256];
        float a[8];
        a[0] = bflo(va.x); a[1] = bfhi(va.x); a[2] = bflo(va.y); a[3] = bfhi(va.y);
        a[4] = bflo(va.z); a[5] = bfhi(va.z); a[6] = bflo(va.w); a[7] = bfhi(va.w);
#pragma unroll
        for (int c = 0; c < 8; c++)
            a[c] = lrelu(fmaf(a[c], sc3[c], sh3[c]));
        float acc = b5v;
#pragma unroll
        for (int o = 0; o < 8; o++) {
            float h = b4f[o];
#pragma unroll
            for (int c = 0; c < 8; c++)
                h = fmaf(a[c], w4f[o][c], h);
            acc = fmaf(lrelu(h), w5[o], acc);
        }
        out[p0 + (size_t)it * 256] = acc;
        va = na;
    }
}

// --------------------------------------------------------------------------
extern "C" void kernel_launch(void* const* d_in, const int* in_sizes, int n_in,
                              void* d_out, int out_size, void* d_ws,
                              size_t ws_size, hipStream_t stream) {
    const float* x   = (const float*)d_in[0];
    const float* W1  = (const float*)d_in[1];
    const float* b1  = (const float*)d_in[2];
    const float* g1  = (const float*)d_in[3];
    const float* be1 = (const float*)d_in[4];
    const float* W2  = (const float*)d_in[5];
    const float* b2  = (const float*)d_in[6];
    const float* g2  = (const float*)d_in[7];
    const float* be2 = (const float*)d_in[8];
    const float* W3  = (const float*)d_in[9];
    const float* b3  = (const float*)d_in[10];
    const float* g3  = (const float*)d_in[11];
    const float* be3 = (const float*)d_in[12];
    const float* W4  = (const float*)d_in[13];
    const float* b4  = (const float*)d_in[14];
    const float* g4  = (const float*)d_in[15];
    const float* be4 = (const float*)d_in[16];
    const float* W5  = (const float*)d_in[17];
    const float* b5  = (const float*)d_in[18];

    float* ws     = (float*)d_ws;
    float* stats1 = ws + 0;     // 4 x 32
    float* raw2   = ws + 128;   // 4 x 32
    float* stats3 = ws + 256;   // 4 x 16
    float* stats4 = ws + 320;   // 4 x 16
    unsigned short* bufA = (unsigned short*)((char*)d_ws + 8192);
    unsigned short* bufB =
        (unsigned short*)((char*)d_ws + 8192 + (size_t)NN * 32u);

    k_prep<<<2, 256, 0, stream>>>(ws);
    k_layer1<<<2304, 256, 0, stream>>>(x, W1, b1, bufA, stats1);
    k_stats2<<<2048, 256, 0, stream>>>(bufA, stats1, g1, be1, W2, raw2);
    k_fuse3<<<2048, 256, 0, stream>>>(bufA, bufB, stats1, g1, be1, W2,
                                      raw2, g2, be2, b2, W3, b3, stats3);
    k_stats4<<<2048, 256, 0, stream>>>(bufB, stats3, g3, be3, W4, b4, stats4);
    k_last<<<2304, 256, 0, stream>>>(bufB, stats3, g3, be3, stats4, g4, be4,
                                     W4, b4, W5, b5, (float*)d_out);
}

// Round 7
// 231.900 us; speedup vs baseline: 5.7430x; 1.0250x over previous
//
#include <hip/hip_runtime.h>
#include <stdint.h>

// ---------------------------------------------------------------------------
// AdjCompute R7.
// Lessons: R3 in-loop weight loads = 7x VALU bloat; R4 per-iter LDS+waitcnt
// = latency collapse; R6 16x16x32 mids waste half the wave on K zero-padding
// (K=16 real channels vs K=32 shape).
// R7: stats2/fuse3 on mfma_f32_32x32x16_bf16 (K=16 exact): all 64 lanes
// stage real act1 data -> 32 positions per staging pass (2x wave-instr
// efficiency). A/B/D layouts HW-verified by R4 (which passed at 0.066):
//   A[i=lane&31][k=(lane>>5)*8+j], B[k=(lane>>5)*8+j][col=lane&31],
//   D: col=lane&31, row=(reg&3)+8*(reg>>2)+4*(lane>>5).
// fuse3 stage1->2 repack = shfl_xor(32) (conflict-free) + cndmask.
//
// Pipeline (6 launches):
//   k_prep    zero stats region
//   k_layer1  MFMA 16x16x32: h1 = W1|x_m-x_n|+b1 -> bufA[pos][16ch] + stats1
//   k_stats2  MFMA 32x32x16: moments of d = W2*act1 (no write)
//   k_fuse3   MFMA 32x32x16 x2: act1 -> d -> act2 -> h3 = W3*act2+b3
//             -> bufB + stats3
//   k_stats4  VALU: stats of h4 = W4*act3+b4 (no write)
//   k_last    VALU: h3 -> act3 -> h4 -> act4 -> out (fp32)
//
// ws layout (floats), all stats 4-replica:
//   [0..128)    stats1  4 x (sum16|ssq16)
//   [128..256)  raw2    4 x (S16|Q16)  of d = h2_pre - b2
//   [256..320)  stats3  4 x (sum8|ssq8)
//   [320..384)  stats4  4 x (sum8|ssq8)
//   byte 8192:             bufA h1: NN*16 bf16 = 75,497,472 B
//   byte 8192+75497472:    bufB h3: NN*8  bf16 = 37,748,736 B
// ---------------------------------------------------------------------------

#define NPTS 1536
#define NN   2359296u
static constexpr float FNN   = 2359296.0f;
static constexpr float EPS   = 1e-5f;
static constexpr float SLOPE = 0.01f;
static constexpr float INV_M = 1.0f / 2359296.0f;

typedef __attribute__((ext_vector_type(8)))  short bf16x8;
typedef __attribute__((ext_vector_type(4)))  float f32x4;
typedef __attribute__((ext_vector_type(16))) float f32x16;
union frag8 { int4 i; bf16x8 v; };

__device__ __forceinline__ float bflo(unsigned u) {
    return __builtin_bit_cast(float, u << 16);
}
__device__ __forceinline__ float bfhi(unsigned u) {
    return __builtin_bit_cast(float, u & 0xffff0000u);
}
__device__ __forceinline__ unsigned short f2bf(float f) {   // RNE
    unsigned u = __builtin_bit_cast(unsigned, f);
    u += 0x7fffu + ((u >> 16) & 1u);
    return (unsigned short)(u >> 16);
}
__device__ __forceinline__ unsigned pack2(float lo, float hi) {
    return (unsigned)f2bf(lo) | ((unsigned)f2bf(hi) << 16);
}
__device__ __forceinline__ unsigned packtr(float lo, float hi) { // trunc
    unsigned a = __builtin_bit_cast(unsigned, lo);
    unsigned b = __builtin_bit_cast(unsigned, hi);
    return (a >> 16) | (b & 0xffff0000u);
}
__device__ __forceinline__ float lrelu(float t) {
    return fmaxf(t, t * SLOPE);
}
__device__ __forceinline__ float4 ld4(const float* p) {
    return *(const float4*)p;
}
__device__ __forceinline__ unsigned shflx32(unsigned v) {
    return (unsigned)__shfl_xor((int)v, 32);
}

// bn over 8 channels from 4-replica 8ch stats (replica stride 16)
__device__ __forceinline__ void bn8_inline(
        const float* __restrict__ stats, const float* __restrict__ g,
        const float* __restrict__ be, float* sc, float* sh) {
#pragma unroll
    for (int c = 0; c < 8; c++) {
        float S = stats[c] + stats[16 + c] + stats[32 + c] + stats[48 + c];
        float Q = stats[8 + c] + stats[24 + c] + stats[40 + c] +
                  stats[56 + c];
        float mu  = S * INV_M;
        float var = fmaf(-mu, mu, Q * INV_M);
        float s   = g[c] * rsqrtf(var + EPS);
        sc[c] = s;
        sh[c] = fmaf(-mu, s, be[c]);
    }
}

// --------------------------------------------------------------------------
__global__ __launch_bounds__(256) void k_prep(float* __restrict__ ws) {
    int t = threadIdx.x;
    if (t < 384) ws[t] = 0.0f;
}

// --------------------------------------------------------------------------
// Layer 1 (unchanged from R6): MFMA A=W1, B=adj -> D[o][m], coalesced stores
__global__ __launch_bounds__(256) void k_layer1(
        const float* __restrict__ x, const float* __restrict__ W1,
        const float* __restrict__ b1, unsigned short* __restrict__ outb,
        float* __restrict__ stats) {
    int tid  = threadIdx.x;
    int lane = tid & 63;
    int wv   = tid >> 6;
    int gid  = blockIdx.x * 4 + wv;
    int mt   = gid % 96;
    int nc   = gid / 96;
    int l15  = lane & 15;
    int quad = lane >> 4;
    int cb   = quad * 8;

    const float* wr = W1 + l15 * 64 + cb;
    float4 w0 = ld4(wr);
    float4 w1 = ld4(wr + 4);
    float4 w2 = ld4(wr + 32);
    float4 w3 = ld4(wr + 36);
    frag8 fb1, fb2;
    fb1.i = make_int4(pack2(w0.x, w0.y), pack2(w0.z, w0.w),
                      pack2(w1.x, w1.y), pack2(w1.z, w1.w));
    fb2.i = make_int4(pack2(w2.x, w2.y), pack2(w2.z, w2.w),
                      pack2(w3.x, w3.y), pack2(w3.z, w3.w));

    const float* xr = x + (mt * 16 + l15) * 64 + cb;
    float4 xa0 = ld4(xr);
    float4 xa1 = ld4(xr + 4);
    float4 xa2 = ld4(xr + 32);
    float4 xa3 = ld4(xr + 36);

    float4 b1v = ld4(b1 + quad * 4);
    float lsum[4] = {0.f, 0.f, 0.f, 0.f};
    float lssq[4] = {0.f, 0.f, 0.f, 0.f};

    int n0 = nc * 16;
    const float* xp = x + (size_t)n0 * 64 + cb;
    float4 uA0 = ld4(xp);
    float4 uA1 = ld4(xp + 4);
    float4 uA2 = ld4(xp + 32);
    float4 uA3 = ld4(xp + 36);
    const float* xq = x + (size_t)(n0 + 1) * 64 + cb;
    float4 uB0 = ld4(xq);
    float4 uB1 = ld4(xq + 4);
    float4 uB2 = ld4(xq + 32);
    float4 uB3 = ld4(xq + 36);

    auto body = [&](int n, float4& u0, float4& u1, float4& u2, float4& u3,
                    int pf) {
        frag8 fa1, fa2;
        fa1.i = make_int4(
            packtr(fabsf(xa0.x - u0.x), fabsf(xa0.y - u0.y)),
            packtr(fabsf(xa0.z - u0.z), fabsf(xa0.w - u0.w)),
            packtr(fabsf(xa1.x - u1.x), fabsf(xa1.y - u1.y)),
            packtr(fabsf(xa1.z - u1.z), fabsf(xa1.w - u1.w)));
        fa2.i = make_int4(
            packtr(fabsf(xa2.x - u2.x), fabsf(xa2.y - u2.y)),
            packtr(fabsf(xa2.z - u2.z), fabsf(xa2.w - u2.w)),
            packtr(fabsf(xa3.x - u3.x), fabsf(xa3.y - u3.y)),
            packtr(fabsf(xa3.z - u3.z), fabsf(xa3.w - u3.w)));
        const float* xf = x + (size_t)pf * 64 + cb;
        u0 = ld4(xf);
        u1 = ld4(xf + 4);
        u2 = ld4(xf + 32);
        u3 = ld4(xf + 36);
        f32x4 acc = {b1v.x, b1v.y, b1v.z, b1v.w};
        acc = __builtin_amdgcn_mfma_f32_16x16x32_bf16(fb1.v, fa1.v, acc, 0, 0, 0);
        acc = __builtin_amdgcn_mfma_f32_16x16x32_bf16(fb2.v, fa2.v, acc, 0, 0, 0);
        size_t pos = (size_t)n * NPTS + mt * 16 + l15;
#pragma unroll
        for (int r = 0; r < 4; r++) {
            lsum[r] += acc[r];
            lssq[r] = fmaf(acc[r], acc[r], lssq[r]);
        }
        *(uint2*)(outb + pos * 16 + quad * 4) =
            make_uint2(pack2(acc[0], acc[1]), pack2(acc[2], acc[3]));
    };

#pragma unroll 1
    for (int i = 0; i < 16; i += 2) {
        int pfA = n0 + ((i + 2 < 16) ? i + 2 : 15);
        int pfB = n0 + ((i + 3 < 16) ? i + 3 : 15);
        body(n0 + i,     uA0, uA1, uA2, uA3, pfA);
        body(n0 + i + 1, uB0, uB1, uB2, uB3, pfB);
    }

#pragma unroll
    for (int off = 1; off < 16; off <<= 1) {
#pragma unroll
        for (int r = 0; r < 4; r++) {
            lsum[r] += __shfl_xor(lsum[r], off);
            lssq[r] += __shfl_xor(lssq[r], off);
        }
    }
    __shared__ float red[4][32];
    if (l15 == 0) {
#pragma unroll
        for (int r = 0; r < 4; r++) {
            red[wv][quad * 4 + r]      = lsum[r];
            red[wv][16 + quad * 4 + r] = lssq[r];
        }
    }
    __syncthreads();
    if (tid < 32) {
        float v = red[0][tid] + red[1][tid] + red[2][tid] + red[3][tid];
        atomicAdd(stats + (blockIdx.x & 3) * 32 + tid, v);
    }
}

// --------------------------------------------------------------------------
// stats2 (32x32x16): A = W2 (rows 0..15 real), B = act1[16k][32pos].
// All 64 lanes stage real data: lane -> pos=lane&31, chans kh*8..kh*8+7.
// D rows o real in regs 0..7: o = (r&3)+8*(r>>2)+4*kh.
__global__ __launch_bounds__(256) void k_stats2(
        const unsigned short* __restrict__ h1,
        const float* __restrict__ stats1, const float* __restrict__ g1,
        const float* __restrict__ be1, const float* __restrict__ W2,
        float* __restrict__ raw2) {
    int tid  = threadIdx.x;
    int lane = tid & 63;
    int wv   = tid >> 6;
    int pc   = lane & 31;
    int kh   = lane >> 5;
    int gid  = blockIdx.x * 4 + wv;

    float sc[8], sh[8];
#pragma unroll
    for (int j = 0; j < 8; j++) {
        int c = kh * 8 + j;
        float S = stats1[c] + stats1[32 + c] + stats1[64 + c] + stats1[96 + c];
        float Q = stats1[16 + c] + stats1[48 + c] + stats1[80 + c] +
                  stats1[112 + c];
        float mu  = S * INV_M;
        float var = fmaf(-mu, mu, Q * INV_M);
        float s   = g1[c] * rsqrtf(var + EPS);
        sc[j] = s;
        sh[j] = fmaf(-mu, s, be1[c]);
    }
    frag8 fw2; fw2.i = make_int4(0, 0, 0, 0);
    if (pc < 16) {
        const float* w = W2 + pc * 16 + kh * 8;
        float4 wa = ld4(w), wb = ld4(w + 4);
        fw2.i = make_int4(pack2(wa.x, wa.y), pack2(wa.z, wa.w),
                          pack2(wb.x, wb.y), pack2(wb.z, wb.w));
    }
    f32x16 z;
#pragma unroll
    for (int r = 0; r < 16; r++) z[r] = 0.0f;

    float sum[8], ssq[8];
#pragma unroll
    for (int r = 0; r < 8; r++) { sum[r] = 0.f; ssq[r] = 0.f; }

    size_t tile0 = (size_t)gid * 9;
    const unsigned short* ptr = h1 + (tile0 * 32 + pc) * 16 + kh * 8;
    uint4 va = *(const uint4*)ptr;
#pragma unroll 1
    for (int it = 0; it < 9; it++) {
        uint4 nx = va;
        if (it + 1 < 9) nx = *(const uint4*)(ptr + (size_t)(it + 1) * 512);
        float a0 = bflo(va.x), a1 = bfhi(va.x);
        float a2 = bflo(va.y), a3 = bfhi(va.y);
        float a4 = bflo(va.z), a5 = bfhi(va.z);
        float a6 = bflo(va.w), a7 = bfhi(va.w);
        a0 = lrelu(fmaf(a0, sc[0], sh[0]));
        a1 = lrelu(fmaf(a1, sc[1], sh[1]));
        a2 = lrelu(fmaf(a2, sc[2], sh[2]));
        a3 = lrelu(fmaf(a3, sc[3], sh[3]));
        a4 = lrelu(fmaf(a4, sc[4], sh[4]));
        a5 = lrelu(fmaf(a5, sc[5], sh[5]));
        a6 = lrelu(fmaf(a6, sc[6], sh[6]));
        a7 = lrelu(fmaf(a7, sc[7], sh[7]));
        frag8 fb;
        fb.i = make_int4(packtr(a0, a1), packtr(a2, a3),
                         packtr(a4, a5), packtr(a6, a7));
        f32x16 d = __builtin_amdgcn_mfma_f32_32x32x16_bf16(fw2.v, fb.v, z, 0, 0, 0);
#pragma unroll
        for (int r = 0; r < 8; r++) {
            sum[r] += d[r];
            ssq[r] = fmaf(d[r], d[r], ssq[r]);
        }
        va = nx;
    }
    // reduce over 32 positions (stays within kh half)
#pragma unroll
    for (int off = 1; off < 32; off <<= 1) {
#pragma unroll
        for (int r = 0; r < 8; r++) {
            sum[r] += __shfl_xor(sum[r], off);
            ssq[r] += __shfl_xor(ssq[r], off);
        }
    }
    __shared__ float red[4][32];
    if (pc == 0) {
#pragma unroll
        for (int r = 0; r < 8; r++) {
            int o = (r & 3) + 8 * (r >> 2) + 4 * kh;
            red[wv][o]      = sum[r];
            red[wv][16 + o] = ssq[r];
        }
    }
    __syncthreads();
    if (tid < 32) {
        float v = red[0][tid] + red[1][tid] + red[2][tid] + red[3][tid];
        atomicAdd(raw2 + (blockIdx.x & 3) * 32 + tid, v);
    }
}

// --------------------------------------------------------------------------
// fuse3 (32x32x16 x2): act1 -> d=W2*act1 -> act2 -> shfl_xor(32) repack
// -> h3 = W3*act2 + b3 -> store + stats3.
__global__ __launch_bounds__(256) void k_fuse3(
        const unsigned short* __restrict__ h1,
        unsigned short* __restrict__ h3out,
        const float* __restrict__ stats1, const float* __restrict__ g1,
        const float* __restrict__ be1, const float* __restrict__ W2,
        const float* __restrict__ raw2, const float* __restrict__ g2,
        const float* __restrict__ be2, const float* __restrict__ b2,
        const float* __restrict__ W3, const float* __restrict__ b3,
        float* __restrict__ stats3) {
    int tid  = threadIdx.x;
    int lane = tid & 63;
    int wv   = tid >> 6;
    int pc   = lane & 31;
    int kh   = lane >> 5;
    int gid  = blockIdx.x * 4 + wv;

    float sc[8], sh[8];
#pragma unroll
    for (int j = 0; j < 8; j++) {
        int c = kh * 8 + j;
        float S = stats1[c] + stats1[32 + c] + stats1[64 + c] + stats1[96 + c];
        float Q = stats1[16 + c] + stats1[48 + c] + stats1[80 + c] +
                  stats1[112 + c];
        float mu  = S * INV_M;
        float var = fmaf(-mu, mu, Q * INV_M);
        float s   = g1[c] * rsqrtf(var + EPS);
        sc[j] = s;
        sh[j] = fmaf(-mu, s, be1[c]);
    }
    // bn2 for this lane's 8 D-rows: o = (r&3)+8*(r>>2)+4*kh  (b2 folded)
    float sc2[8], sh2[8];
#pragma unroll
    for (int r = 0; r < 8; r++) {
        int c = (r & 3) + 8 * (r >> 2) + 4 * kh;
        float S = raw2[c] + raw2[32 + c] + raw2[64 + c] + raw2[96 + c];
        float Q = raw2[16 + c] + raw2[48 + c] + raw2[80 + c] + raw2[112 + c];
        float bc = b2[c];
        float sm = S + FNN * bc;
        float sq = Q + 2.0f * bc * S + FNN * bc * bc;
        float mu  = sm * INV_M;
        float var = fmaf(-mu, mu, sq * INV_M);
        float s   = g2[c] * rsqrtf(var + EPS);
        float shv = fmaf(-mu, s, be2[c]);
        sc2[r] = s;
        sh2[r] = fmaf(s, bc, shv);
    }
    frag8 fw2; fw2.i = make_int4(0, 0, 0, 0);
    if (pc < 16) {
        const float* w = W2 + pc * 16 + kh * 8;
        float4 wa = ld4(w), wb = ld4(w + 4);
        fw2.i = make_int4(pack2(wa.x, wa.y), pack2(wa.z, wa.w),
                          pack2(wb.x, wb.y), pack2(wb.z, wb.w));
    }
    frag8 fw3; fw3.i = make_int4(0, 0, 0, 0);
    if (pc < 8) {
        const float* w = W3 + pc * 16 + kh * 8;
        float4 wa = ld4(w), wb = ld4(w + 4);
        fw3.i = make_int4(pack2(wa.x, wa.y), pack2(wa.z, wa.w),
                          pack2(wb.x, wb.y), pack2(wb.z, wb.w));
    }
    float b3r[4];
#pragma unroll
    for (int r = 0; r < 4; r++) b3r[r] = b3[kh * 4 + r];

    f32x16 z;
#pragma unroll
    for (int r = 0; r < 16; r++) z[r] = 0.0f;

    float sum3[4] = {0.f, 0.f, 0.f, 0.f}, ssq3[4] = {0.f, 0.f, 0.f, 0.f};

    size_t tile0 = (size_t)gid * 9;
    const unsigned short* ptr = h1 + (tile0 * 32 + pc) * 16 + kh * 8;
    uint4 va = *(const uint4*)ptr;
#pragma unroll 1
    for (int it = 0; it < 9; it++) {
        uint4 nx = va;
        if (it + 1 < 9) nx = *(const uint4*)(ptr + (size_t)(it + 1) * 512);
        float a0 = bflo(va.x), a1 = bfhi(va.x);
        float a2 = bflo(va.y), a3 = bfhi(va.y);
        float a4 = bflo(va.z), a5 = bfhi(va.z);
        float a6 = bflo(va.w), a7 = bfhi(va.w);
        a0 = lrelu(fmaf(a0, sc[0], sh[0]));
        a1 = lrelu(fmaf(a1, sc[1], sh[1]));
        a2 = lrelu(fmaf(a2, sc[2], sh[2]));
        a3 = lrelu(fmaf(a3, sc[3], sh[3]));
        a4 = lrelu(fmaf(a4, sc[4], sh[4]));
        a5 = lrelu(fmaf(a5, sc[5], sh[5]));
        a6 = lrelu(fmaf(a6, sc[6], sh[6]));
        a7 = lrelu(fmaf(a7, sc[7], sh[7]));
        frag8 fb;
        fb.i = make_int4(packtr(a0, a1), packtr(a2, a3),
                         packtr(a4, a5), packtr(a6, a7));
        f32x16 d = __builtin_amdgcn_mfma_f32_32x32x16_bf16(fw2.v, fb.v, z, 0, 0, 0);
        // act2 on 8 real regs (rows o = (r&3)+8*(r>>2)+4kh)
        float t0 = lrelu(fmaf(d[0], sc2[0], sh2[0]));
        float t1 = lrelu(fmaf(d[1], sc2[1], sh2[1]));
        float t2 = lrelu(fmaf(d[2], sc2[2], sh2[2]));
        float t3 = lrelu(fmaf(d[3], sc2[3], sh2[3]));
        float t4 = lrelu(fmaf(d[4], sc2[4], sh2[4]));
        float t5 = lrelu(fmaf(d[5], sc2[5], sh2[5]));
        float t6 = lrelu(fmaf(d[6], sc2[6], sh2[6]));
        float t7 = lrelu(fmaf(d[7], sc2[7], sh2[7]));
        // pack: wlo = o 4kh+{0..3}, whi = o 8+4kh+{0..3}
        unsigned w0 = packtr(t0, t1), w1 = packtr(t2, t3);
        unsigned w2 = packtr(t4, t5), w3 = packtr(t6, t7);
        // exchange with lane^32: kh=0 sends (w2,w3)=o{8..11}, needs o{4..7};
        // kh=1 sends (w0,w1)=o{4..7}, needs o{8..11}.
        unsigned p0 = kh ? w0 : w2;
        unsigned p1 = kh ? w1 : w3;
        unsigned q0 = shflx32(p0);
        unsigned q1 = shflx32(p1);
        // B-frag for stage-2: k = kh*8+j -> act2 chans kh*8..kh*8+7
        // kh=0: (w0,w1,q0,q1) = o{0..3}+o{4..7}; kh=1: (q0,q1,w2,w3)
        frag8 fb2;
        fb2.i = make_int4(kh ? q0 : w0, kh ? q1 : w1,
                          kh ? w2 : q0, kh ? w3 : q1);
        f32x16 d2 = __builtin_amdgcn_mfma_f32_32x32x16_bf16(fw3.v, fb2.v, z, 0, 0, 0);
        // real rows: regs 0..3 -> o3 = (reg&3)+4kh
        float h0 = d2[0] + b3r[0];
        float h1v = d2[1] + b3r[1];
        float h2 = d2[2] + b3r[2];
        float h3v = d2[3] + b3r[3];
        sum3[0] += h0;  ssq3[0] = fmaf(h0, h0, ssq3[0]);
        sum3[1] += h1v; ssq3[1] = fmaf(h1v, h1v, ssq3[1]);
        sum3[2] += h2;  ssq3[2] = fmaf(h2, h2, ssq3[2]);
        sum3[3] += h3v; ssq3[3] = fmaf(h3v, h3v, ssq3[3]);
        size_t pos = (tile0 + it) * 32 + pc;
        *(uint2*)(h3out + pos * 8 + kh * 4) =
            make_uint2(pack2(h0, h1v), pack2(h2, h3v));
        va = nx;
    }
#pragma unroll
    for (int off = 1; off < 32; off <<= 1) {
#pragma unroll
        for (int r = 0; r < 4; r++) {
            sum3[r] += __shfl_xor(sum3[r], off);
            ssq3[r] += __shfl_xor(ssq3[r], off);
        }
    }
    __shared__ float red[4][16];
    if (pc == 0) {
#pragma unroll
        for (int r = 0; r < 4; r++) {
            red[wv][kh * 4 + r]     = sum3[r];
            red[wv][8 + kh * 4 + r] = ssq3[r];
        }
    }
    __syncthreads();
    if (tid < 16) {
        float v = red[0][tid] + red[1][tid] + red[2][tid] + red[3][tid];
        atomicAdd(stats3 + (blockIdx.x & 3) * 16 + tid, v);
    }
}

// --------------------------------------------------------------------------
// stats4 (VALU, unchanged): read h3, inline bn3, h4 = W4*act3 + b4 -> stats4
__global__ __launch_bounds__(256) void k_stats4(
        const unsigned short* __restrict__ h3,
        const float* __restrict__ stats3, const float* __restrict__ g3,
        const float* __restrict__ be3, const float* __restrict__ W4,
        const float* __restrict__ b4, float* __restrict__ stats4) {
    int tid = threadIdx.x;
    int og1 = tid & 1;

    float sc[8], sh[8];
    bn8_inline(stats3, g3, be3, sc, sh);

    float w[4][8];
#pragma unroll
    for (int j = 0; j < 4; j++) {
        const float* wr = W4 + (og1 * 4 + j) * 8;
        float4 v0 = ld4(wr);
        float4 v1 = ld4(wr + 4);
        w[j][0] = v0.x; w[j][1] = v0.y; w[j][2] = v0.z; w[j][3] = v0.w;
        w[j][4] = v1.x; w[j][5] = v1.y; w[j][6] = v1.z; w[j][7] = v1.w;
    }
    float bi[4];
#pragma unroll
    for (int j = 0; j < 4; j++) bi[j] = b4[og1 * 4 + j];

    float sum[4] = {0.f, 0.f, 0.f, 0.f}, ssq[4] = {0.f, 0.f, 0.f, 0.f};

    size_t p0 = (size_t)blockIdx.x * 1152 + (tid >> 1);
    const uint4* src = (const uint4*)h3 + p0;
    uint4 va = src[0];
#pragma unroll 1
    for (int it = 0; it < 9; it++) {
        int itn = (it + 1 < 9) ? it + 1 : 8;
        uint4 na = src[(size_t)itn * 128];
        float a[8];
        a[0] = bflo(va.x); a[1] = bfhi(va.x); a[2] = bflo(va.y); a[3] = bfhi(va.y);
        a[4] = bflo(va.z); a[5] = bfhi(va.z); a[6] = bflo(va.w); a[7] = bfhi(va.w);
#pragma unroll
        for (int c = 0; c < 8; c++)
            a[c] = lrelu(fmaf(a[c], sc[c], sh[c]));
        float d[4] = {bi[0], bi[1], bi[2], bi[3]};
#pragma unroll
        for (int c = 0; c < 8; c++) {
#pragma unroll
            for (int j = 0; j < 4; j++)
                d[j] = fmaf(a[c], w[j][c], d[j]);
        }
#pragma unroll
        for (int j = 0; j < 4; j++) {
            sum[j] += d[j];
            ssq[j] = fmaf(d[j], d[j], ssq[j]);
        }
        va = na;
    }
#pragma unroll
    for (int off = 2; off < 64; off <<= 1) {
#pragma unroll
        for (int j = 0; j < 4; j++) {
            sum[j] += __shfl_xor(sum[j], off);
            ssq[j] += __shfl_xor(ssq[j], off);
        }
    }
    __shared__ float red[4][16];
    int wv = tid >> 6, lane = tid & 63;
    if (lane < 2) {
#pragma unroll
        for (int j = 0; j < 4; j++) {
            red[wv][og1 * 4 + j]     = sum[j];
            red[wv][8 + og1 * 4 + j] = ssq[j];
        }
    }
    __syncthreads();
    if (tid < 16) {
        float v = red[0][tid] + red[1][tid] + red[2][tid] + red[3][tid];
        atomicAdd(stats4 + (blockIdx.x & 3) * 16 + tid, v);
    }
}

// --------------------------------------------------------------------------
// last (VALU, unchanged): h3 -> act3 -> h4 (bn4-folded W4) -> act4 -> out
__global__ __launch_bounds__(256) void k_last(
        const unsigned short* __restrict__ h3,
        const float* __restrict__ stats3, const float* __restrict__ g3,
        const float* __restrict__ be3, const float* __restrict__ stats4,
        const float* __restrict__ g4, const float* __restrict__ be4,
        const float* __restrict__ W4, const float* __restrict__ b4,
        const float* __restrict__ W5, const float* __restrict__ b5,
        float* __restrict__ out) {
    int tid = threadIdx.x;

    float sc3[8], sh3[8];
    bn8_inline(stats3, g3, be3, sc3, sh3);

    float w4f[8][8], b4f[8], w5[8];
#pragma unroll
    for (int o = 0; o < 8; o++) {
        float S = stats4[o] + stats4[16 + o] + stats4[32 + o] + stats4[48 + o];
        float Q = stats4[8 + o] + stats4[24 + o] + stats4[40 + o] +
                  stats4[56 + o];
        float mu  = S * INV_M;
        float var = fmaf(-mu, mu, Q * INV_M);
        float s   = g4[o] * rsqrtf(var + EPS);
        float shv = fmaf(-mu, s, be4[o]);
        b4f[o] = fmaf(s, b4[o], shv);
        const float* wr = W4 + o * 8;
        float4 v0 = ld4(wr);
        float4 v1 = ld4(wr + 4);
        w4f[o][0] = s * v0.x; w4f[o][1] = s * v0.y;
        w4f[o][2] = s * v0.z; w4f[o][3] = s * v0.w;
        w4f[o][4] = s * v1.x; w4f[o][5] = s * v1.y;
        w4f[o][6] = s * v1.z; w4f[o][7] = s * v1.w;
        w5[o] = W5[o];
    }
    float b5v = b5[0];

    size_t p0 = (size_t)blockIdx.x * 1024 + tid;
    const uint4* src = (const uint4*)h3 + p0;
    uint4 va = src[0];
#pragma unroll 1
    for (int it = 0; it < 4; it++) {
        int itn = (it + 1 < 4) ? it + 1 : 3;
        uint4 na = src[(size_t)itn * 256];
        float a[8];
        a[0] = bflo(va.x); a[1] = bfhi(va.x); a[2] = bflo(va.y); a[3] = bfhi(va.y);
        a[4] = bflo(va.z); a[5] = bfhi(va.z); a[6] = bflo(va.w); a[7] = bfhi(va.w);
#pragma unroll
        for (int c = 0; c < 8; c++)
            a[c] = lrelu(fmaf(a[c], sc3[c], sh3[c]));
        float acc = b5v;
#pragma unroll
        for (int o = 0; o < 8; o++) {
            float h = b4f[o];
#pragma unroll
            for (int c = 0; c < 8; c++)
                h = fmaf(a[c], w4f[o][c], h);
            acc = fmaf(lrelu(h), w5[o], acc);
        }
        out[p0 + (size_t)it * 256] = acc;
        va = na;
    }
}

// --------------------------------------------------------------------------
extern "C" void kernel_launch(void* const* d_in, const int* in_sizes, int n_in,
                              void* d_out, int out_size, void* d_ws,
                              size_t ws_size, hipStream_t stream) {
    const float* x   = (const float*)d_in[0];
    const float* W1  = (const float*)d_in[1];
    const float* b1  = (const float*)d_in[2];
    const float* g1  = (const float*)d_in[3];
    const float* be1 = (const float*)d_in[4];
    const float* W2  = (const float*)d_in[5];
    const float* b2  = (const float*)d_in[6];
    const float* g2  = (const float*)d_in[7];
    const float* be2 = (const float*)d_in[8];
    const float* W3  = (const float*)d_in[9];
    const float* b3  = (const float*)d_in[10];
    const float* g3  = (const float*)d_in[11];
    const float* be3 = (const float*)d_in[12];
    const float* W4  = (const float*)d_in[13];
    const float* b4  = (const float*)d_in[14];
    const float* g4  = (const float*)d_in[15];
    const float* be4 = (const float*)d_in[16];
    const float* W5  = (const float*)d_in[17];
    const float* b5  = (const float*)d_in[18];

    float* ws     = (float*)d_ws;
    float* stats1 = ws + 0;     // 4 x 32
    float* raw2   = ws + 128;   // 4 x 32
    float* stats3 = ws + 256;   // 4 x 16
    float* stats4 = ws + 320;   // 4 x 16
    unsigned short* bufA = (unsigned short*)((char*)d_ws + 8192);
    unsigned short* bufB =
        (unsigned short*)((char*)d_ws + 8192 + (size_t)NN * 32u);

    k_prep<<<2, 256, 0, stream>>>(ws);
    k_layer1<<<2304, 256, 0, stream>>>(x, W1, b1, bufA, stats1);
    k_stats2<<<2048, 256, 0, stream>>>(bufA, stats1, g1, be1, W2, raw2);
    k_fuse3<<<2048, 256, 0, stream>>>(bufA, bufB, stats1, g1, be1, W2,
                                      raw2, g2, be2, b2, W3, b3, stats3);
    k_stats4<<<2048, 256, 0, stream>>>(bufB, stats3, g3, be3, W4, b4, stats4);
    k_last<<<2304, 256, 0, stream>>>(bufB, stats3, g3, be3, stats4, g4, be4,
                                     W4, b4, W5, b5, (float*)d_out);
}

// Round 8
// 231.828 us; speedup vs baseline: 5.7448x; 1.0003x over previous
//
#include <hip/hip_runtime.h>
#include <stdint.h>

// ---------------------------------------------------------------------------
// AdjCompute R8.
// Lessons: R3 in-loop weight loads = VALU bloat; R4 per-iter LDS+waitcnt =
// latency collapse; R7 32x32x16 mids correct but latency-serialized (all
// pipes <45% busy, 1-deep prefetch vs 400-900cyc load latency).
// R8: ILP pass - pair-interleaved tile streams (stats2/stats4), ring-2
// prefetch (fuse3), up-front loads (last), v_perm 1-instr trunc packs.
// Math identical to R7 (passed at absmax 0.0703).
//
// Pipeline (6 launches):
//   k_prep    zero stats region
//   k_layer1  MFMA 16x16x32: h1 = W1|x_m-x_n|+b1 -> bufA[pos][16ch] + stats1
//   k_stats2  MFMA 32x32x16: moments of d = W2*act1 (no write)
//   k_fuse3   MFMA 32x32x16 x2: act1 -> d -> act2 -> h3 = W3*act2+b3
//             -> bufB + stats3
//   k_stats4  VALU: stats of h4 = W4*act3+b4 (no write)
//   k_last    VALU: h3 -> act3 -> h4 -> act4 -> out (fp32)
//
// ws layout (floats), all stats 4-replica:
//   [0..128)    stats1  4 x (sum16|ssq16)
//   [128..256)  raw2    4 x (S16|Q16)  of d = h2_pre - b2
//   [256..320)  stats3  4 x (sum8|ssq8)
//   [320..384)  stats4  4 x (sum8|ssq8)
//   byte 8192:             bufA h1: NN*16 bf16 = 75,497,472 B
//   byte 8192+75497472:    bufB h3: NN*8  bf16 = 37,748,736 B
//
// MFMA layouts (HW-verified R4/R7):
//   16x16x32: A[i=lane&15][k=quad*8+j], D col=lane&15,row=quad*4+reg
//   32x32x16: A[i=lane&31][k=(lane>>5)*8+j], B[k=(lane>>5)*8+j][col=lane&31],
//             D col=lane&31, row=(reg&3)+8*(reg>>2)+4*(lane>>5)
// ---------------------------------------------------------------------------

#define NPTS 1536
#define NN   2359296u
static constexpr float FNN   = 2359296.0f;
static constexpr float EPS   = 1e-5f;
static constexpr float SLOPE = 0.01f;
static constexpr float INV_M = 1.0f / 2359296.0f;

typedef __attribute__((ext_vector_type(8)))  short bf16x8;
typedef __attribute__((ext_vector_type(4)))  float f32x4;
typedef __attribute__((ext_vector_type(16))) float f32x16;
union frag8 { int4 i; bf16x8 v; };

__device__ __forceinline__ float bflo(unsigned u) {
    return __builtin_bit_cast(float, u << 16);
}
__device__ __forceinline__ float bfhi(unsigned u) {
    return __builtin_bit_cast(float, u & 0xffff0000u);
}
__device__ __forceinline__ unsigned short f2bf(float f) {   // RNE
    unsigned u = __builtin_bit_cast(unsigned, f);
    u += 0x7fffu + ((u >> 16) & 1u);
    return (unsigned short)(u >> 16);
}
__device__ __forceinline__ unsigned pack2(float lo, float hi) {  // RNE pair
    return (unsigned)f2bf(lo) | ((unsigned)f2bf(hi) << 16);
}
// truncation pack via v_perm_b32 (1 instr); bit-identical to shift/and/or
__device__ __forceinline__ unsigned packtr(float lo, float hi) {
    unsigned a = __builtin_bit_cast(unsigned, lo);
    unsigned b = __builtin_bit_cast(unsigned, hi);
#if __has_builtin(__builtin_amdgcn_perm)
    return __builtin_amdgcn_perm(b, a, 0x07060302u);  // hi-src=b, lo-src=a
#else
    return (a >> 16) | (b & 0xffff0000u);
#endif
}
__device__ __forceinline__ float lrelu(float t) {
    return fmaxf(t, t * SLOPE);
}
__device__ __forceinline__ float4 ld4(const float* p) {
    return *(const float4*)p;
}
__device__ __forceinline__ unsigned shflx32(unsigned v) {
    return (unsigned)__shfl_xor((int)v, 32);
}

// bn over 8 channels from 4-replica 8ch stats (replica stride 16)
__device__ __forceinline__ void bn8_inline(
        const float* __restrict__ stats, const float* __restrict__ g,
        const float* __restrict__ be, float* sc, float* sh) {
#pragma unroll
    for (int c = 0; c < 8; c++) {
        float S = stats[c] + stats[16 + c] + stats[32 + c] + stats[48 + c];
        float Q = stats[8 + c] + stats[24 + c] + stats[40 + c] +
                  stats[56 + c];
        float mu  = S * INV_M;
        float var = fmaf(-mu, mu, Q * INV_M);
        float s   = g[c] * rsqrtf(var + EPS);
        sc[c] = s;
        sh[c] = fmaf(-mu, s, be[c]);
    }
}

// --------------------------------------------------------------------------
__global__ __launch_bounds__(256) void k_prep(float* __restrict__ ws) {
    int t = threadIdx.x;
    if (t < 384) ws[t] = 0.0f;
}

// --------------------------------------------------------------------------
// Layer 1 (structure unchanged from R6/R7; packtr now v_perm)
__global__ __launch_bounds__(256) void k_layer1(
        const float* __restrict__ x, const float* __restrict__ W1,
        const float* __restrict__ b1, unsigned short* __restrict__ outb,
        float* __restrict__ stats) {
    int tid  = threadIdx.x;
    int lane = tid & 63;
    int wv   = tid >> 6;
    int gid  = blockIdx.x * 4 + wv;
    int mt   = gid % 96;
    int nc   = gid / 96;
    int l15  = lane & 15;
    int quad = lane >> 4;
    int cb   = quad * 8;

    const float* wr = W1 + l15 * 64 + cb;
    float4 w0 = ld4(wr);
    float4 w1 = ld4(wr + 4);
    float4 w2 = ld4(wr + 32);
    float4 w3 = ld4(wr + 36);
    frag8 fb1, fb2;
    fb1.i = make_int4(pack2(w0.x, w0.y), pack2(w0.z, w0.w),
                      pack2(w1.x, w1.y), pack2(w1.z, w1.w));
    fb2.i = make_int4(pack2(w2.x, w2.y), pack2(w2.z, w2.w),
                      pack2(w3.x, w3.y), pack2(w3.z, w3.w));

    const float* xr = x + (mt * 16 + l15) * 64 + cb;
    float4 xa0 = ld4(xr);
    float4 xa1 = ld4(xr + 4);
    float4 xa2 = ld4(xr + 32);
    float4 xa3 = ld4(xr + 36);

    float4 b1v = ld4(b1 + quad * 4);
    float lsum[4] = {0.f, 0.f, 0.f, 0.f};
    float lssq[4] = {0.f, 0.f, 0.f, 0.f};

    int n0 = nc * 16;
    const float* xp = x + (size_t)n0 * 64 + cb;
    float4 uA0 = ld4(xp);
    float4 uA1 = ld4(xp + 4);
    float4 uA2 = ld4(xp + 32);
    float4 uA3 = ld4(xp + 36);
    const float* xq = x + (size_t)(n0 + 1) * 64 + cb;
    float4 uB0 = ld4(xq);
    float4 uB1 = ld4(xq + 4);
    float4 uB2 = ld4(xq + 32);
    float4 uB3 = ld4(xq + 36);

    auto body = [&](int n, float4& u0, float4& u1, float4& u2, float4& u3,
                    int pf) {
        frag8 fa1, fa2;
        fa1.i = make_int4(
            packtr(fabsf(xa0.x - u0.x), fabsf(xa0.y - u0.y)),
            packtr(fabsf(xa0.z - u0.z), fabsf(xa0.w - u0.w)),
            packtr(fabsf(xa1.x - u1.x), fabsf(xa1.y - u1.y)),
            packtr(fabsf(xa1.z - u1.z), fabsf(xa1.w - u1.w)));
        fa2.i = make_int4(
            packtr(fabsf(xa2.x - u2.x), fabsf(xa2.y - u2.y)),
            packtr(fabsf(xa2.z - u2.z), fabsf(xa2.w - u2.w)),
            packtr(fabsf(xa3.x - u3.x), fabsf(xa3.y - u3.y)),
            packtr(fabsf(xa3.z - u3.z), fabsf(xa3.w - u3.w)));
        const float* xf = x + (size_t)pf * 64 + cb;
        u0 = ld4(xf);
        u1 = ld4(xf + 4);
        u2 = ld4(xf + 32);
        u3 = ld4(xf + 36);
        f32x4 acc = {b1v.x, b1v.y, b1v.z, b1v.w};
        acc = __builtin_amdgcn_mfma_f32_16x16x32_bf16(fb1.v, fa1.v, acc, 0, 0, 0);
        acc = __builtin_amdgcn_mfma_f32_16x16x32_bf16(fb2.v, fa2.v, acc, 0, 0, 0);
        size_t pos = (size_t)n * NPTS + mt * 16 + l15;
#pragma unroll
        for (int r = 0; r < 4; r++) {
            lsum[r] += acc[r];
            lssq[r] = fmaf(acc[r], acc[r], lssq[r]);
        }
        *(uint2*)(outb + pos * 16 + quad * 4) =
            make_uint2(pack2(acc[0], acc[1]), pack2(acc[2], acc[3]));
    };

#pragma unroll 1
    for (int i = 0; i < 16; i += 2) {
        int pfA = n0 + ((i + 2 < 16) ? i + 2 : 15);
        int pfB = n0 + ((i + 3 < 16) ? i + 3 : 15);
        body(n0 + i,     uA0, uA1, uA2, uA3, pfA);
        body(n0 + i + 1, uB0, uB1, uB2, uB3, pfB);
    }

#pragma unroll
    for (int off = 1; off < 16; off <<= 1) {
#pragma unroll
        for (int r = 0; r < 4; r++) {
            lsum[r] += __shfl_xor(lsum[r], off);
            lssq[r] += __shfl_xor(lssq[r], off);
        }
    }
    __shared__ float red[4][32];
    if (l15 == 0) {
#pragma unroll
        for (int r = 0; r < 4; r++) {
            red[wv][quad * 4 + r]      = lsum[r];
            red[wv][16 + quad * 4 + r] = lssq[r];
        }
    }
    __syncthreads();
    if (tid < 32) {
        float v = red[0][tid] + red[1][tid] + red[2][tid] + red[3][tid];
        atomicAdd(stats + (blockIdx.x & 3) * 32 + tid, v);
    }
}

// --------------------------------------------------------------------------
// stats2 (32x32x16, pair-interleaved: 8 tiles/wave as 4 pairs, 4 outstanding
// loads). grid 2304.
__global__ __launch_bounds__(256, 4) void k_stats2(
        const unsigned short* __restrict__ h1,
        const float* __restrict__ stats1, const float* __restrict__ g1,
        const float* __restrict__ be1, const float* __restrict__ W2,
        float* __restrict__ raw2) {
    int tid  = threadIdx.x;
    int lane = tid & 63;
    int wv   = tid >> 6;
    int pc   = lane & 31;
    int kh   = lane >> 5;
    int gid  = blockIdx.x * 4 + wv;

    float sc[8], sh[8];
#pragma unroll
    for (int j = 0; j < 8; j++) {
        int c = kh * 8 + j;
        float S = stats1[c] + stats1[32 + c] + stats1[64 + c] + stats1[96 + c];
        float Q = stats1[16 + c] + stats1[48 + c] + stats1[80 + c] +
                  stats1[112 + c];
        float mu  = S * INV_M;
        float var = fmaf(-mu, mu, Q * INV_M);
        float s   = g1[c] * rsqrtf(var + EPS);
        sc[j] = s;
        sh[j] = fmaf(-mu, s, be1[c]);
    }
    frag8 fw2; fw2.i = make_int4(0, 0, 0, 0);
    if (pc < 16) {
        const float* w = W2 + pc * 16 + kh * 8;
        float4 wa = ld4(w), wb = ld4(w + 4);
        fw2.i = make_int4(pack2(wa.x, wa.y), pack2(wa.z, wa.w),
                          pack2(wb.x, wb.y), pack2(wb.z, wb.w));
    }
    f32x16 z;
#pragma unroll
    for (int r = 0; r < 16; r++) z[r] = 0.0f;

    float sum[8], ssq[8];
#pragma unroll
    for (int r = 0; r < 8; r++) { sum[r] = 0.f; ssq[r] = 0.f; }

    size_t tile0 = (size_t)gid * 8;
    const unsigned short* ptr = h1 + (tile0 * 32 + pc) * 16 + kh * 8;

    auto proc = [&](uint4 v) {
        float a0 = bflo(v.x), a1 = bfhi(v.x);
        float a2 = bflo(v.y), a3 = bfhi(v.y);
        float a4 = bflo(v.z), a5 = bfhi(v.z);
        float a6 = bflo(v.w), a7 = bfhi(v.w);
        a0 = lrelu(fmaf(a0, sc[0], sh[0]));
        a1 = lrelu(fmaf(a1, sc[1], sh[1]));
        a2 = lrelu(fmaf(a2, sc[2], sh[2]));
        a3 = lrelu(fmaf(a3, sc[3], sh[3]));
        a4 = lrelu(fmaf(a4, sc[4], sh[4]));
        a5 = lrelu(fmaf(a5, sc[5], sh[5]));
        a6 = lrelu(fmaf(a6, sc[6], sh[6]));
        a7 = lrelu(fmaf(a7, sc[7], sh[7]));
        frag8 fb;
        fb.i = make_int4(packtr(a0, a1), packtr(a2, a3),
                         packtr(a4, a5), packtr(a6, a7));
        f32x16 d = __builtin_amdgcn_mfma_f32_32x32x16_bf16(fw2.v, fb.v, z, 0, 0, 0);
#pragma unroll
        for (int r = 0; r < 8; r++) {
            sum[r] += d[r];
            ssq[r] = fmaf(d[r], d[r], ssq[r]);
        }
    };

    uint4 vA = *(const uint4*)(ptr);
    uint4 vB = *(const uint4*)(ptr + 512);
#pragma unroll 1
    for (int p = 0; p < 4; p++) {
        uint4 nA = vA, nB = vB;
        if (p < 3) {
            nA = *(const uint4*)(ptr + (size_t)(2 * p + 2) * 512);
            nB = *(const uint4*)(ptr + (size_t)(2 * p + 3) * 512);
        }
        proc(vA);
        proc(vB);
        vA = nA; vB = nB;
    }

#pragma unroll
    for (int off = 1; off < 32; off <<= 1) {
#pragma unroll
        for (int r = 0; r < 8; r++) {
            sum[r] += __shfl_xor(sum[r], off);
            ssq[r] += __shfl_xor(ssq[r], off);
        }
    }
    __shared__ float red[4][32];
    if (pc == 0) {
#pragma unroll
        for (int r = 0; r < 8; r++) {
            int o = (r & 3) + 8 * (r >> 2) + 4 * kh;
            red[wv][o]      = sum[r];
            red[wv][16 + o] = ssq[r];
        }
    }
    __syncthreads();
    if (tid < 32) {
        float v = red[0][tid] + red[1][tid] + red[2][tid] + red[3][tid];
        atomicAdd(raw2 + (blockIdx.x & 3) * 32 + tid, v);
    }
}

// --------------------------------------------------------------------------
// fuse3 (32x32x16 x2, ring-2 prefetch: 2 outstanding loads). grid 2304,
// 8 tiles/wave.
__global__ __launch_bounds__(256, 3) void k_fuse3(
        const unsigned short* __restrict__ h1,
        unsigned short* __restrict__ h3out,
        const float* __restrict__ stats1, const float* __restrict__ g1,
        const float* __restrict__ be1, const float* __restrict__ W2,
        const float* __restrict__ raw2, const float* __restrict__ g2,
        const float* __restrict__ be2, const float* __restrict__ b2,
        const float* __restrict__ W3, const float* __restrict__ b3,
        float* __restrict__ stats3) {
    int tid  = threadIdx.x;
    int lane = tid & 63;
    int wv   = tid >> 6;
    int pc   = lane & 31;
    int kh   = lane >> 5;
    int gid  = blockIdx.x * 4 + wv;

    float sc[8], sh[8];
#pragma unroll
    for (int j = 0; j < 8; j++) {
        int c = kh * 8 + j;
        float S = stats1[c] + stats1[32 + c] + stats1[64 + c] + stats1[96 + c];
        float Q = stats1[16 + c] + stats1[48 + c] + stats1[80 + c] +
                  stats1[112 + c];
        float mu  = S * INV_M;
        float var = fmaf(-mu, mu, Q * INV_M);
        float s   = g1[c] * rsqrtf(var + EPS);
        sc[j] = s;
        sh[j] = fmaf(-mu, s, be1[c]);
    }
    float sc2[8], sh2[8];
#pragma unroll
    for (int r = 0; r < 8; r++) {
        int c = (r & 3) + 8 * (r >> 2) + 4 * kh;
        float S = raw2[c] + raw2[32 + c] + raw2[64 + c] + raw2[96 + c];
        float Q = raw2[16 + c] + raw2[48 + c] + raw2[80 + c] + raw2[112 + c];
        float bc = b2[c];
        float sm = S + FNN * bc;
        float sq = Q + 2.0f * bc * S + FNN * bc * bc;
        float mu  = sm * INV_M;
        float var = fmaf(-mu, mu, sq * INV_M);
        float s   = g2[c] * rsqrtf(var + EPS);
        float shv = fmaf(-mu, s, be2[c]);
        sc2[r] = s;
        sh2[r] = fmaf(s, bc, shv);
    }
    frag8 fw2; fw2.i = make_int4(0, 0, 0, 0);
    if (pc < 16) {
        const float* w = W2 + pc * 16 + kh * 8;
        float4 wa = ld4(w), wb = ld4(w + 4);
        fw2.i = make_int4(pack2(wa.x, wa.y), pack2(wa.z, wa.w),
                          pack2(wb.x, wb.y), pack2(wb.z, wb.w));
    }
    frag8 fw3; fw3.i = make_int4(0, 0, 0, 0);
    if (pc < 8) {
        const float* w = W3 + pc * 16 + kh * 8;
        float4 wa = ld4(w), wb = ld4(w + 4);
        fw3.i = make_int4(pack2(wa.x, wa.y), pack2(wa.z, wa.w),
                          pack2(wb.x, wb.y), pack2(wb.z, wb.w));
    }
    float b3r[4];
#pragma unroll
    for (int r = 0; r < 4; r++) b3r[r] = b3[kh * 4 + r];

    f32x16 z;
#pragma unroll
    for (int r = 0; r < 16; r++) z[r] = 0.0f;

    float sum3[4] = {0.f, 0.f, 0.f, 0.f}, ssq3[4] = {0.f, 0.f, 0.f, 0.f};

    size_t tile0 = (size_t)gid * 8;
    const unsigned short* ptr = h1 + (tile0 * 32 + pc) * 16 + kh * 8;

    uint4 v0 = *(const uint4*)(ptr);
    uint4 v1 = *(const uint4*)(ptr + 512);
#pragma unroll 1
    for (int it = 0; it < 8; it++) {
        uint4 nx = v0;
        if (it + 2 < 8)
            nx = *(const uint4*)(ptr + (size_t)(it + 2) * 512);
        float a0 = bflo(v0.x), a1 = bfhi(v0.x);
        float a2 = bflo(v0.y), a3 = bfhi(v0.y);
        float a4 = bflo(v0.z), a5 = bfhi(v0.z);
        float a6 = bflo(v0.w), a7 = bfhi(v0.w);
        a0 = lrelu(fmaf(a0, sc[0], sh[0]));
        a1 = lrelu(fmaf(a1, sc[1], sh[1]));
        a2 = lrelu(fmaf(a2, sc[2], sh[2]));
        a3 = lrelu(fmaf(a3, sc[3], sh[3]));
        a4 = lrelu(fmaf(a4, sc[4], sh[4]));
        a5 = lrelu(fmaf(a5, sc[5], sh[5]));
        a6 = lrelu(fmaf(a6, sc[6], sh[6]));
        a7 = lrelu(fmaf(a7, sc[7], sh[7]));
        frag8 fb;
        fb.i = make_int4(packtr(a0, a1), packtr(a2, a3),
                         packtr(a4, a5), packtr(a6, a7));
        f32x16 d = __builtin_amdgcn_mfma_f32_32x32x16_bf16(fw2.v, fb.v, z, 0, 0, 0);
        float t0 = lrelu(fmaf(d[0], sc2[0], sh2[0]));
        float t1 = lrelu(fmaf(d[1], sc2[1], sh2[1]));
        float t2 = lrelu(fmaf(d[2], sc2[2], sh2[2]));
        float t3 = lrelu(fmaf(d[3], sc2[3], sh2[3]));
        float t4 = lrelu(fmaf(d[4], sc2[4], sh2[4]));
        float t5 = lrelu(fmaf(d[5], sc2[5], sh2[5]));
        float t6 = lrelu(fmaf(d[6], sc2[6], sh2[6]));
        float t7 = lrelu(fmaf(d[7], sc2[7], sh2[7]));
        unsigned w0 = packtr(t0, t1), w1 = packtr(t2, t3);
        unsigned w2 = packtr(t4, t5), w3 = packtr(t6, t7);
        unsigned p0 = kh ? w0 : w2;
        unsigned p1 = kh ? w1 : w3;
        unsigned q0 = shflx32(p0);
        unsigned q1 = shflx32(p1);
        frag8 fb2;
        fb2.i = make_int4(kh ? q0 : w0, kh ? q1 : w1,
                          kh ? w2 : q0, kh ? w3 : q1);
        f32x16 d2 = __builtin_amdgcn_mfma_f32_32x32x16_bf16(fw3.v, fb2.v, z, 0, 0, 0);
        float h0 = d2[0] + b3r[0];
        float h1v = d2[1] + b3r[1];
        float h2 = d2[2] + b3r[2];
        float h3v = d2[3] + b3r[3];
        sum3[0] += h0;  ssq3[0] = fmaf(h0, h0, ssq3[0]);
        sum3[1] += h1v; ssq3[1] = fmaf(h1v, h1v, ssq3[1]);
        sum3[2] += h2;  ssq3[2] = fmaf(h2, h2, ssq3[2]);
        sum3[3] += h3v; ssq3[3] = fmaf(h3v, h3v, ssq3[3]);
        size_t pos = (tile0 + it) * 32 + pc;
        *(uint2*)(h3out + pos * 8 + kh * 4) =
            make_uint2(pack2(h0, h1v), pack2(h2, h3v));
        v0 = v1; v1 = nx;
    }
#pragma unroll
    for (int off = 1; off < 32; off <<= 1) {
#pragma unroll
        for (int r = 0; r < 4; r++) {
            sum3[r] += __shfl_xor(sum3[r], off);
            ssq3[r] += __shfl_xor(ssq3[r], off);
        }
    }
    __shared__ float red[4][16];
    if (pc == 0) {
#pragma unroll
        for (int r = 0; r < 4; r++) {
            red[wv][kh * 4 + r]     = sum3[r];
            red[wv][8 + kh * 4 + r] = ssq3[r];
        }
    }
    __syncthreads();
    if (tid < 16) {
        float v = red[0][tid] + red[1][tid] + red[2][tid] + red[3][tid];
        atomicAdd(stats3 + (blockIdx.x & 3) * 16 + tid, v);
    }
}

// --------------------------------------------------------------------------
// stats4 (VALU, pair-interleaved: 8 positions per thread-pair). grid 2304.
__global__ __launch_bounds__(256, 4) void k_stats4(
        const unsigned short* __restrict__ h3,
        const float* __restrict__ stats3, const float* __restrict__ g3,
        const float* __restrict__ be3, const float* __restrict__ W4,
        const float* __restrict__ b4, float* __restrict__ stats4) {
    int tid = threadIdx.x;
    int og1 = tid & 1;

    float sc[8], sh[8];
    bn8_inline(stats3, g3, be3, sc, sh);

    float w[4][8];
#pragma unroll
    for (int j = 0; j < 4; j++) {
        const float* wr = W4 + (og1 * 4 + j) * 8;
        float4 v0 = ld4(wr);
        float4 v1 = ld4(wr + 4);
        w[j][0] = v0.x; w[j][1] = v0.y; w[j][2] = v0.z; w[j][3] = v0.w;
        w[j][4] = v1.x; w[j][5] = v1.y; w[j][6] = v1.z; w[j][7] = v1.w;
    }
    float bi[4];
#pragma unroll
    for (int j = 0; j < 4; j++) bi[j] = b4[og1 * 4 + j];

    float sum[4] = {0.f, 0.f, 0.f, 0.f}, ssq[4] = {0.f, 0.f, 0.f, 0.f};

    size_t p0 = (size_t)blockIdx.x * 1024 + (tid >> 1);
    const uint4* src = (const uint4*)h3 + p0;

    auto proc = [&](uint4 v) {
        float a[8];
        a[0] = bflo(v.x); a[1] = bfhi(v.x); a[2] = bflo(v.y); a[3] = bfhi(v.y);
        a[4] = bflo(v.z); a[5] = bfhi(v.z); a[6] = bflo(v.w); a[7] = bfhi(v.w);
#pragma unroll
        for (int c = 0; c < 8; c++)
            a[c] = lrelu(fmaf(a[c], sc[c], sh[c]));
        float d[4] = {bi[0], bi[1], bi[2], bi[3]};
#pragma unroll
        for (int c = 0; c < 8; c++) {
#pragma unroll
            for (int j = 0; j < 4; j++)
                d[j] = fmaf(a[c], w[j][c], d[j]);
        }
#pragma unroll
        for (int j = 0; j < 4; j++) {
            sum[j] += d[j];
            ssq[j] = fmaf(d[j], d[j], ssq[j]);
        }
    };

    uint4 vA = src[0];
    uint4 vB = src[128];
#pragma unroll 1
    for (int p = 0; p < 4; p++) {
        uint4 nA = vA, nB = vB;
        if (p < 3) {
            nA = src[(size_t)(2 * p + 2) * 128];
            nB = src[(size_t)(2 * p + 3) * 128];
        }
        proc(vA);
        proc(vB);
        vA = nA; vB = nB;
    }
#pragma unroll
    for (int off = 2; off < 64; off <<= 1) {
#pragma unroll
        for (int j = 0; j < 4; j++) {
            sum[j] += __shfl_xor(sum[j], off);
            ssq[j] += __shfl_xor(ssq[j], off);
        }
    }
    __shared__ float red[4][16];
    int wv = tid >> 6, lane = tid & 63;
    if (lane < 2) {
#pragma unroll
        for (int j = 0; j < 4; j++) {
            red[wv][og1 * 4 + j]     = sum[j];
            red[wv][8 + og1 * 4 + j] = ssq[j];
        }
    }
    __syncthreads();
    if (tid < 16) {
        float v = red[0][tid] + red[1][tid] + red[2][tid] + red[3][tid];
        atomicAdd(stats4 + (blockIdx.x & 3) * 16 + tid, v);
    }
}

// --------------------------------------------------------------------------
// last (VALU): 4 positions/thread, all loads issued up-front. grid 2304.
__global__ __launch_bounds__(256, 4) void k_last(
        const unsigned short* __restrict__ h3,
        const float* __restrict__ stats3, const float* __restrict__ g3,
        const float* __restrict__ be3, const float* __restrict__ stats4,
        const float* __restrict__ g4, const float* __restrict__ be4,
        const float* __restrict__ W4, const float* __restrict__ b4,
        const float* __restrict__ W5, const float* __restrict__ b5,
        float* __restrict__ out) {
    int tid = threadIdx.x;

    float sc3[8], sh3[8];
    bn8_inline(stats3, g3, be3, sc3, sh3);

    float w4f[8][8], b4f[8], w5[8];
#pragma unroll
    for (int o = 0; o < 8; o++) {
        float S = stats4[o] + stats4[16 + o] + stats4[32 + o] + stats4[48 + o];
        float Q = stats4[8 + o] + stats4[24 + o] + stats4[40 + o] +
                  stats4[56 + o];
        float mu  = S * INV_M;
        float var = fmaf(-mu, mu, Q * INV_M);
        float s   = g4[o] * rsqrtf(var + EPS);
        float shv = fmaf(-mu, s, be4[o]);
        b4f[o] = fmaf(s, b4[o], shv);
        const float* wr = W4 + o * 8;
        float4 v0 = ld4(wr);
        float4 v1 = ld4(wr + 4);
        w4f[o][0] = s * v0.x; w4f[o][1] = s * v0.y;
        w4f[o][2] = s * v0.z; w4f[o][3] = s * v0.w;
        w4f[o][4] = s * v1.x; w4f[o][5] = s * v1.y;
        w4f[o][6] = s * v1.z; w4f[o][7] = s * v1.w;
        w5[o] = W5[o];
    }
    float b5v = b5[0];

    size_t p0 = (size_t)blockIdx.x * 1024 + tid;
    const uint4* src = (const uint4*)h3 + p0;
    uint4 vv[4];
    vv[0] = src[0];
    vv[1] = src[256];
    vv[2] = src[512];
    vv[3] = src[768];
#pragma unroll
    for (int it = 0; it < 4; it++) {
        uint4 va = vv[it];
        float a[8];
        a[0] = bflo(va.x); a[1] = bfhi(va.x); a[2] = bflo(va.y); a[3] = bfhi(va.y);
        a[4] = bflo(va.z); a[5] = bfhi(va.z); a[6] = bflo(va.w); a[7] = bfhi(va.w);
#pragma unroll
        for (int c = 0; c < 8; c++)
            a[c] = lrelu(fmaf(a[c], sc3[c], sh3[c]));
        float acc = b5v;
#pragma unroll
        for (int o = 0; o < 8; o++) {
            float h = b4f[o];
#pragma unroll
            for (int c = 0; c < 8; c++)
                h = fmaf(a[c], w4f[o][c], h);
            acc = fmaf(lrelu(h), w5[o], acc);
        }
        out[p0 + (size_t)it * 256] = acc;
    }
}

// --------------------------------------------------------------------------
extern "C" void kernel_launch(void* const* d_in, const int* in_sizes, int n_in,
                              void* d_out, int out_size, void* d_ws,
                              size_t ws_size, hipStream_t stream) {
    const float* x   = (const float*)d_in[0];
    const float* W1  = (const float*)d_in[1];
    const float* b1  = (const float*)d_in[2];
    const float* g1  = (const float*)d_in[3];
    const float* be1 = (const float*)d_in[4];
    const float* W2  = (const float*)d_in[5];
    const float* b2  = (const float*)d_in[6];
    const float* g2  = (const float*)d_in[7];
    const float* be2 = (const float*)d_in[8];
    const float* W3  = (const float*)d_in[9];
    const float* b3  = (const float*)d_in[10];
    const float* g3  = (const float*)d_in[11];
    const float* be3 = (const float*)d_in[12];
    const float* W4  = (const float*)d_in[13];
    const float* b4  = (const float*)d_in[14];
    const float* g4  = (const float*)d_in[15];
    const float* be4 = (const float*)d_in[16];
    const float* W5  = (const float*)d_in[17];
    const float* b5  = (const float*)d_in[18];

    float* ws     = (float*)d_ws;
    float* stats1 = ws + 0;     // 4 x 32
    float* raw2   = ws + 128;   // 4 x 32
    float* stats3 = ws + 256;   // 4 x 16
    float* stats4 = ws + 320;   // 4 x 16
    unsigned short* bufA = (unsigned short*)((char*)d_ws + 8192);
    unsigned short* bufB =
        (unsigned short*)((char*)d_ws + 8192 + (size_t)NN * 32u);

    k_prep<<<2, 256, 0, stream>>>(ws);
    k_layer1<<<2304, 256, 0, stream>>>(x, W1, b1, bufA, stats1);
    k_stats2<<<2304, 256, 0, stream>>>(bufA, stats1, g1, be1, W2, raw2);
    k_fuse3<<<2304, 256, 0, stream>>>(bufA, bufB, stats1, g1, be1, W2,
                                      raw2, g2, be2, b2, W3, b3, stats3);
    k_stats4<<<2304, 256, 0, stream>>>(bufB, stats3, g3, be3, W4, b4, stats4);
    k_last<<<2304, 256, 0, stream>>>(bufB, stats3, g3, be3, stats4, g4, be4,
                                     W4, b4, W5, b5, (float*)d_out);
}